// Round 4
// baseline (383.638 us; speedup 1.0000x reference)
//
#include <hip/hip_runtime.h>
#include <math.h>

using f32x4  = __attribute__((ext_vector_type(4))) float;
using bf16x8 = __attribute__((ext_vector_type(8))) short;

typedef const __attribute__((address_space(1))) void gas_void;
typedef __attribute__((address_space(3))) void las_void;

__device__ __forceinline__ void gl16(const void* g, void* l) {
    __builtin_amdgcn_global_load_lds((gas_void*)g, (las_void*)l, 16, 0, 0);
}

__device__ __forceinline__ unsigned short f2bf(float f) {
    union { float f; unsigned u; } v; v.f = f;
    unsigned r = v.u + 0x7fffu + ((v.u >> 16) & 1u);   // RNE
    return (unsigned short)(r >> 16);
}
__device__ __forceinline__ float bf2f(unsigned short u) {
    return __uint_as_float(((unsigned)u) << 16);
}

// ---------------- prep: X (NCHW fp32) -> patch-major bf16 Xp[36864][768] ----------------
__global__ void pcl_prep_x(const float* __restrict__ x, unsigned short* __restrict__ xp) {
    int t = threadIdx.x;              // 256
    int wv = t >> 6, l = t & 63;
    int p = blockIdx.x * 4 + wv;      // patch id
    int b = p / 576, n = p % 576;
    int ph = n / 24, pw = n % 24;
    const float* base = x + ((size_t)(b * 3)) * 147456 + (ph * 16) * 384 + pw * 16;
    unsigned* dst = (unsigned*)(xp + (size_t)p * 768);
#pragma unroll
    for (int q = 0; q < 6; ++q) {
        int k = q * 128 + l * 2;
        int c = k >> 8, i = (k >> 4) & 15, j = k & 15;
        const float* s = base + (size_t)c * 147456 + i * 384 + j;
        float2 v = *(const float2*)s;
        unsigned lo = f2bf(v.x), hi = f2bf(v.y);
        dst[q * 64 + l] = lo | (hi << 16);
    }
}

// ---------------- prep: W -> bf16; latents -> row-normalized bf16 ----------------
__global__ void pcl_prep_wl(const float* __restrict__ w,
                            const float* __restrict__ l1, const float* __restrict__ l2,
                            unsigned short* __restrict__ wsW,
                            unsigned short* __restrict__ wsL) {
    int r = blockIdx.x, t = threadIdx.x;   // 2816 x 64
    if (r < 768) {
        const float* src = w + (size_t)r * 768;
        unsigned short* dst = wsW + (size_t)r * 768;
#pragma unroll
        for (int i = 0; i < 12; ++i) dst[t + 64 * i] = f2bf(src[t + 64 * i]);
    } else {
        int lr = r - 768;
        const float* src = (lr < 1024) ? l1 + (size_t)lr * 768 : l2 + (size_t)(lr - 1024) * 768;
        unsigned short* dst = wsL + (size_t)lr * 768;
        float vals[12];
        float s = 0.f;
#pragma unroll
        for (int i = 0; i < 12; ++i) {
            float f = bf2f(f2bf(src[t + 64 * i]));
            vals[i] = f; s += f * f;
        }
#pragma unroll
        for (int off = 32; off; off >>= 1) s += __shfl_xor(s, off, 64);
        float rn = 1.0f / sqrtf(s);
#pragma unroll
        for (int i = 0; i < 12; ++i) dst[t + 64 * i] = f2bf(vals[i] * rn);
    }
}

// ================= K1: conv GEMM, M=64 x N=768(whole), writes P over xp, fuses rpn ======
// LDS: A0 8K @0 | A1 8K @8192 | B 96K @16384 (768 rows x 128B) | nrm 2K @114688
#define K1_LDS 116736

__global__ __launch_bounds__(512, 1)
void pcl_k1(const unsigned short* __restrict__ xp,
            const unsigned short* __restrict__ wsW,
            const float* __restrict__ bias,
            unsigned short* __restrict__ pbuf,      // == xp region (safe in-place)
            float* __restrict__ rpn) {
    extern __shared__ char smem[];
    char* A0 = smem; char* A1 = smem + 8192; char* BB = smem + 16384;
    float* nrm = (float*)(smem + 114688);
    const int t = threadIdx.x, w = t >> 6, l = t & 63;
    const size_t Mb = (size_t)blockIdx.x * 64;
    const int ir = l >> 3, s2 = (l & 7) ^ ir;
    const int lm = l & 15, lg4 = l >> 4;

    f32x4 acc[6][4];
#pragma unroll
    for (int dt = 0; dt < 6; ++dt)
#pragma unroll
        for (int m = 0; m < 4; ++m) acc[dt][m] = (f32x4)0.f;

    // prologue: stage A(kc=0)
    gl16(xp + (Mb + w * 8 + ir) * 768 + s2 * 8, A0 + w * 1024);

    for (int kc = 0; kc < 12; ++kc) {
        __syncthreads();   // previous compute done -> B free
#pragma unroll
        for (int rep = 0; rep < 12; ++rep) {
            int c2 = w + 8 * rep;                     // 0..95
            gl16(wsW + (size_t)(c2 * 8 + ir) * 768 + kc * 64 + s2 * 8, BB + c2 * 1024);
        }
        if (kc < 11)
            gl16(xp + (Mb + w * 8 + ir) * 768 + (kc + 1) * 64 + s2 * 8,
                 ((kc & 1) ? A0 : A1) + w * 1024);
        __syncthreads();   // staged tiles ready (vmcnt drained)

        const char* A = (kc & 1) ? A1 : A0;
        bf16x8 a[2][4];
#pragma unroll
        for (int ks = 0; ks < 2; ++ks)
#pragma unroll
            for (int m = 0; m < 4; ++m) {
                int r = m * 16 + lm, slot = ks * 4 + lg4;
                a[ks][m] = *(const bf16x8*)(A + r * 128 + ((slot ^ (r & 7)) << 4));
            }
#pragma unroll
        for (int dt = 0; dt < 6; ++dt) {
            int rb = dt * 128 + w * 16 + lm;
#pragma unroll
            for (int ks = 0; ks < 2; ++ks) {
                int slot = ks * 4 + lg4;
                bf16x8 bb = *(const bf16x8*)(BB + rb * 128 + ((slot ^ (rb & 7)) << 4));
#pragma unroll
                for (int m = 0; m < 4; ++m)
                    acc[dt][m] = __builtin_amdgcn_mfma_f32_16x16x32_bf16(a[ks][m], bb, acc[dt][m], 0, 0, 0);
            }
        }
    }

    // epilogue: bias add, bf16 P write (in-place), row sum-of-squares
    float rs[4][4];
#pragma unroll
    for (int m = 0; m < 4; ++m)
#pragma unroll
        for (int j = 0; j < 4; ++j) rs[m][j] = 0.f;
#pragma unroll
    for (int dt = 0; dt < 6; ++dt) {
        int d = dt * 128 + w * 16 + lm;
        float bv = bias[d];
#pragma unroll
        for (int m = 0; m < 4; ++m)
#pragma unroll
            for (int j = 0; j < 4; ++j) {
                int r = m * 16 + lg4 * 4 + j;
                unsigned short h = f2bf(acc[dt][m][j] + bv);
                pbuf[(Mb + r) * 768 + d] = h;
                float fv = bf2f(h);
                rs[m][j] += fv * fv;
            }
    }
#pragma unroll
    for (int m = 0; m < 4; ++m)
#pragma unroll
        for (int j = 0; j < 4; ++j) {
            rs[m][j] += __shfl_xor(rs[m][j], 1);
            rs[m][j] += __shfl_xor(rs[m][j], 2);
            rs[m][j] += __shfl_xor(rs[m][j], 4);
            rs[m][j] += __shfl_xor(rs[m][j], 8);
        }
    if (lm == 0) {
#pragma unroll
        for (int m = 0; m < 4; ++m)
#pragma unroll
            for (int j = 0; j < 4; ++j) nrm[w * 64 + m * 16 + lg4 * 4 + j] = rs[m][j];
    }
    __syncthreads();
    if (t < 64) {
        float s = 0.f;
#pragma unroll
        for (int i = 0; i < 8; ++i) s += nrm[i * 64 + t];
        rpn[Mb + t] = 1.0f / sqrtf(s);
    }
}

// ================= K2: score GEMM 256x256 tiles + exp-sum epilogue =================
// grid 1152 = 144 M-tiles x 8 N-tiles; 8 waves as 2(M)x4(N), wave tile 128x64
// LDS: A0 32K @0 | B0 32K @32768 | A1 @65536 | B1 @98304 | rpnL 1K @131072
#define K2_LDS 132096

__global__ __launch_bounds__(512, 1)
void pcl_k2(const unsigned short* __restrict__ pbuf,
            const unsigned short* __restrict__ wsL,
            const float* __restrict__ rpn,
            double* __restrict__ partials) {
    extern __shared__ char smem[];
    float* rpnL = (float*)(smem + 131072);
    const int t = threadIdx.x, w = t >> 6, l = t & 63;
    const int blk = blockIdx.x;
    const int mt = blk >> 3, nt = blk & 7;
    const size_t Mb = (size_t)mt * 256;
    const int Nb = nt * 256;
    const int wm = w >> 2, wn = w & 3;
    const int ir = l >> 3, s2 = (l & 7) ^ ir;
    const int lm = l & 15, lg4 = l >> 4;

    if (t < 256) rpnL[t] = rpn[Mb + t];

    auto stage = [&](int kc, char* base) {
#pragma unroll
        for (int rep = 0; rep < 4; ++rep) {
            int c2 = w * 4 + rep;                     // 0..31
            gl16(pbuf + (Mb + c2 * 8 + ir) * 768 + kc * 64 + s2 * 8, base + c2 * 1024);
            gl16(wsL + (size_t)(Nb + c2 * 8 + ir) * 768 + kc * 64 + s2 * 8,
                 base + 32768 + c2 * 1024);
        }
    };

    f32x4 acc[8][4];
#pragma unroll
    for (int m = 0; m < 8; ++m)
#pragma unroll
        for (int nb = 0; nb < 4; ++nb) acc[m][nb] = (f32x4)0.f;

    stage(0, smem);
    __syncthreads();

    for (int kc = 0; kc < 12; ++kc) {
        char* cur = smem + (kc & 1) * 65536;
        if (kc < 11) stage(kc + 1, smem + ((kc + 1) & 1) * 65536);
#pragma unroll
        for (int ks = 0; ks < 2; ++ks) {
            int slot = ks * 4 + lg4;
            bf16x8 a[8], b[4];
#pragma unroll
            for (int m = 0; m < 8; ++m) {
                int r = wm * 128 + m * 16 + lm;
                a[m] = *(const bf16x8*)(cur + r * 128 + ((slot ^ (r & 7)) << 4));
            }
#pragma unroll
            for (int nb = 0; nb < 4; ++nb) {
                int rb = wn * 64 + nb * 16 + lm;
                b[nb] = *(const bf16x8*)(cur + 32768 + rb * 128 + ((slot ^ (rb & 7)) << 4));
            }
#pragma unroll
            for (int m = 0; m < 8; ++m)
#pragma unroll
                for (int nb = 0; nb < 4; ++nb)
                    acc[m][nb] = __builtin_amdgcn_mfma_f32_16x16x32_bf16(a[m], b[nb], acc[m][nb], 0, 0, 0);
        }
        __syncthreads();
    }

    // epilogue: exp(2*cos) with batch lo/hi split (boundary is 16-aligned)
    int b0 = (int)(Mb / 576);
    int brl = (b0 + 1) * 576 - (int)Mb;    // local boundary row; may be >= 256
    double slo = 0.0, shi = 0.0;
#pragma unroll
    for (int m = 0; m < 8; ++m) {
        int rl = wm * 128 + m * 16;
        float es = 0.f;
#pragma unroll
        for (int nb = 0; nb < 4; ++nb)
#pragma unroll
            for (int j = 0; j < 4; ++j)
                es += __expf(2.0f * acc[m][nb][j] * rpnL[rl + lg4 * 4 + j]);
        if (rl < brl) slo += (double)es; else shi += (double)es;
    }
#pragma unroll
    for (int off = 32; off; off >>= 1) {
        slo += __shfl_down(slo, off);
        shi += __shfl_down(shi, off);
    }
    __syncthreads();
    double* red = (double*)smem;
    if (l == 0) { red[w * 2] = slo; red[w * 2 + 1] = shi; }
    __syncthreads();
    if (t == 0) {
        double lo = 0.0, hi = 0.0;
#pragma unroll
        for (int i = 0; i < 8; ++i) { lo += red[i * 2]; hi += red[i * 2 + 1]; }
        partials[blk * 2]     = lo;
        partials[blk * 2 + 1] = hi;
    }
}

// ---------------- finish: gather per-batch, log-ratio, mean ----------------
__global__ void pcl_finish(const double* __restrict__ partials, float* __restrict__ out) {
    int b = threadIdx.x;   // 64 batches
    double far = 0.0, close = 0.0;
    for (int mt = 0; mt < 144; ++mt) {
        int b0 = (mt * 256) / 576;
        for (int nt = 0; nt < 8; ++nt) {
            int blk = mt * 8 + nt;
            bool isfar = nt < 4;
            if (b0 == b) {
                double v = partials[blk * 2];
                if (isfar) far += v; else close += v;
            }
            if (b0 + 1 == b) {
                double v = partials[blk * 2 + 1];
                if (isfar) far += v; else close += v;
            }
        }
    }
    double lb = log(far) - log(close);
#pragma unroll
    for (int off = 32; off; off >>= 1) lb += __shfl_down(lb, off);
    if (b == 0) out[0] = (float)(lb * (1.0 / 64.0));
}

extern "C" void kernel_launch(void* const* d_in, const int* in_sizes, int n_in,
                              void* d_out, int out_size, void* d_ws, size_t ws_size,
                              hipStream_t stream) {
    const float* x    = (const float*)d_in[0];
    const float* w    = (const float*)d_in[1];
    const float* bias = (const float*)d_in[2];
    const float* l1   = (const float*)d_in[3];
    const float* l2   = (const float*)d_in[4];
    float* out = (float*)d_out;

    unsigned short* xp  = (unsigned short*)d_ws;                        // 36864*768 bf16 (reused as P)
    unsigned short* wsW = (unsigned short*)((char*)d_ws + 56623104);    // 768*768 bf16
    unsigned short* wsL = (unsigned short*)((char*)d_ws + 57802752);    // 2048*768 bf16
    float* rpn          = (float*)((char*)d_ws + 60948480);             // 36864 f32
    double* partials    = (double*)((char*)d_ws + 61095936);            // 1152*2 f64

    (void)hipFuncSetAttribute((const void*)pcl_k1,
                              hipFuncAttributeMaxDynamicSharedMemorySize, K1_LDS);
    (void)hipFuncSetAttribute((const void*)pcl_k2,
                              hipFuncAttributeMaxDynamicSharedMemorySize, K2_LDS);

    pcl_prep_x<<<9216, 256, 0, stream>>>(x, xp);
    pcl_prep_wl<<<2816, 64, 0, stream>>>(w, l1, l2, wsW, wsL);
    pcl_k1<<<576, 512, K1_LDS, stream>>>(xp, wsW, bias, xp, rpn);
    pcl_k2<<<1152, 512, K2_LDS, stream>>>(xp, wsL, rpn, partials);
    pcl_finish<<<1, 64, 0, stream>>>(partials, out);
}

// Round 6
// 251.402 us; speedup vs baseline: 1.5260x; 1.5260x over previous
//
#include <hip/hip_runtime.h>
#include <math.h>

using f32x4  = __attribute__((ext_vector_type(4))) float;
using bf16x8 = __attribute__((ext_vector_type(8))) short;

typedef const __attribute__((address_space(1))) void gas_void;
typedef __attribute__((address_space(3))) void las_void;

__device__ __forceinline__ void gl16(const void* g, void* l) {
    __builtin_amdgcn_global_load_lds((gas_void*)g, (las_void*)l, 16, 0, 0);
}

__device__ __forceinline__ unsigned short f2bf(float f) {
    union { float f; unsigned u; } v; v.f = f;
    unsigned r = v.u + 0x7fffu + ((v.u >> 16) & 1u);   // RNE
    return (unsigned short)(r >> 16);
}
__device__ __forceinline__ float bf2f(unsigned short u) {
    return __uint_as_float(((unsigned)u) << 16);
}

#define VW2() asm volatile("s_waitcnt vmcnt(2)")
#define VW0() asm volatile("s_waitcnt vmcnt(0)")
#define BAR() __builtin_amdgcn_s_barrier()

// ---------------- prep: X (NCHW fp32) -> patch-major bf16 Xp[36864][768] ----------------
__global__ void pcl_prep_x(const float* __restrict__ x, unsigned short* __restrict__ xp) {
    int t = threadIdx.x;              // 256
    int wv = t >> 6, l = t & 63;
    int p = blockIdx.x * 4 + wv;      // patch id
    int b = p / 576, n = p % 576;
    int ph = n / 24, pw = n % 24;
    const float* base = x + ((size_t)(b * 3)) * 147456 + (ph * 16) * 384 + pw * 16;
    unsigned* dst = (unsigned*)(xp + (size_t)p * 768);
#pragma unroll
    for (int q = 0; q < 6; ++q) {
        int k = q * 128 + l * 2;
        int c = k >> 8, i = (k >> 4) & 15, j = k & 15;
        const float* s = base + (size_t)c * 147456 + i * 384 + j;
        float2 v = *(const float2*)s;
        unsigned lo = f2bf(v.x), hi = f2bf(v.y);
        dst[q * 64 + l] = lo | (hi << 16);
    }
}

// ---------------- prep: W -> bf16; latents -> row-normalized bf16 ----------------
__global__ void pcl_prep_wl(const float* __restrict__ w,
                            const float* __restrict__ l1, const float* __restrict__ l2,
                            unsigned short* __restrict__ wsW,
                            unsigned short* __restrict__ wsL) {
    int r = blockIdx.x, t = threadIdx.x;   // 2816 x 64
    if (r < 768) {
        const float* src = w + (size_t)r * 768;
        unsigned short* dst = wsW + (size_t)r * 768;
#pragma unroll
        for (int i = 0; i < 12; ++i) dst[t + 64 * i] = f2bf(src[t + 64 * i]);
    } else {
        int lr = r - 768;
        const float* src = (lr < 1024) ? l1 + (size_t)lr * 768 : l2 + (size_t)(lr - 1024) * 768;
        unsigned short* dst = wsL + (size_t)lr * 768;
        float vals[12];
        float s = 0.f;
#pragma unroll
        for (int i = 0; i < 12; ++i) {
            float f = bf2f(f2bf(src[t + 64 * i]));
            vals[i] = f; s += f * f;
        }
#pragma unroll
        for (int off = 32; off; off >>= 1) s += __shfl_xor(s, off, 64);
        float rn = 1.0f / sqrtf(s);
#pragma unroll
        for (int i = 0; i < 12; ++i) dst[t + 64 * i] = f2bf(vals[i] * rn);
    }
}

// ================= K1: conv GEMM, M=64 x N=768, writes P over xp, rpn to global ======
// (R4-proven epilogue: norms from bf16-rounded P, cross-wave LDS reduction)
// LDS: A0 8K @0 | A1 8K @8192 | B 96K @16384 | nrm 2K @114688
#define K1_LDS 116736

__global__ __launch_bounds__(512, 1)
void pcl_k1(const unsigned short* __restrict__ xp,
            const unsigned short* __restrict__ wsW,
            const float* __restrict__ bias,
            unsigned short* __restrict__ pbuf,      // == xp region (safe in-place)
            float* __restrict__ rpn) {
    extern __shared__ char smem[];
    char* A0 = smem; char* A1 = smem + 8192; char* BB = smem + 16384;
    float* nrm = (float*)(smem + 114688);
    const int t = threadIdx.x, w = t >> 6, l = t & 63;
    const size_t Mb = (size_t)blockIdx.x * 64;
    const int ir = l >> 3, s2 = (l & 7) ^ ir;
    const int lm = l & 15, lg4 = l >> 4;

    f32x4 acc[6][4];
#pragma unroll
    for (int dt = 0; dt < 6; ++dt)
#pragma unroll
        for (int m = 0; m < 4; ++m) acc[dt][m] = (f32x4)0.f;

    gl16(xp + (Mb + w * 8 + ir) * 768 + s2 * 8, A0 + w * 1024);

    for (int kc = 0; kc < 12; ++kc) {
        __syncthreads();
#pragma unroll
        for (int rep = 0; rep < 12; ++rep) {
            int c2 = w + 8 * rep;                     // 0..95
            gl16(wsW + (size_t)(c2 * 8 + ir) * 768 + kc * 64 + s2 * 8, BB + c2 * 1024);
        }
        if (kc < 11)
            gl16(xp + (Mb + w * 8 + ir) * 768 + (kc + 1) * 64 + s2 * 8,
                 ((kc & 1) ? A0 : A1) + w * 1024);
        __syncthreads();

        const char* A = (kc & 1) ? A1 : A0;
        bf16x8 a[2][4];
#pragma unroll
        for (int ks = 0; ks < 2; ++ks)
#pragma unroll
            for (int m = 0; m < 4; ++m) {
                int r = m * 16 + lm, slot = ks * 4 + lg4;
                a[ks][m] = *(const bf16x8*)(A + r * 128 + ((slot ^ (r & 7)) << 4));
            }
#pragma unroll
        for (int dt = 0; dt < 6; ++dt) {
            int rb = dt * 128 + w * 16 + lm;
#pragma unroll
            for (int ks = 0; ks < 2; ++ks) {
                int slot = ks * 4 + lg4;
                bf16x8 bb = *(const bf16x8*)(BB + rb * 128 + ((slot ^ (rb & 7)) << 4));
#pragma unroll
                for (int m = 0; m < 4; ++m)
                    acc[dt][m] = __builtin_amdgcn_mfma_f32_16x16x32_bf16(a[ks][m], bb, acc[dt][m], 0, 0, 0);
            }
        }
    }

    // epilogue (R4-proven): bias add, bf16 P write (in-place), row sum-of-squares
    float rs[4][4];
#pragma unroll
    for (int m = 0; m < 4; ++m)
#pragma unroll
        for (int j = 0; j < 4; ++j) rs[m][j] = 0.f;
#pragma unroll
    for (int dt = 0; dt < 6; ++dt) {
        int d = dt * 128 + w * 16 + lm;
        float bv = bias[d];
#pragma unroll
        for (int m = 0; m < 4; ++m)
#pragma unroll
            for (int j = 0; j < 4; ++j) {
                int r = m * 16 + lg4 * 4 + j;
                unsigned short h = f2bf(acc[dt][m][j] + bv);
                pbuf[(Mb + r) * 768 + d] = h;
                float fv = bf2f(h);
                rs[m][j] += fv * fv;
            }
    }
#pragma unroll
    for (int m = 0; m < 4; ++m)
#pragma unroll
        for (int j = 0; j < 4; ++j) {
            rs[m][j] += __shfl_xor(rs[m][j], 1);
            rs[m][j] += __shfl_xor(rs[m][j], 2);
            rs[m][j] += __shfl_xor(rs[m][j], 4);
            rs[m][j] += __shfl_xor(rs[m][j], 8);
        }
    if (lm == 0) {
#pragma unroll
        for (int m = 0; m < 4; ++m)
#pragma unroll
            for (int j = 0; j < 4; ++j) nrm[w * 64 + m * 16 + lg4 * 4 + j] = rs[m][j];
    }
    __syncthreads();
    if (t < 64) {
        float s = 0.f;
#pragma unroll
        for (int i = 0; i < 8; ++i) s += nrm[i * 64 + t];
        rpn[Mb + t] = 1.0f / sqrtf(s);
    }
}

// ================= K2: score GEMM 256x256, 8-phase + counted vmcnt + exp-sum =========
// grid 1152 = 144 M-tiles x 8 N-tiles; 8 waves 2(M)x4(N), wave tile 128x64
// LDS: buf0 {A 32K | B 32K} @0 | buf1 @65536  = 128 KiB
#define K2_LDS 131072

__global__ __launch_bounds__(512, 1)
void pcl_k2(const unsigned short* __restrict__ pbuf,
            const unsigned short* __restrict__ wsL,
            const float* __restrict__ rpn,
            double* __restrict__ partials) {
    extern __shared__ char smem[];
    const int t = threadIdx.x, w = t >> 6, l = t & 63;
    const int blk = blockIdx.x;
    const int mt = blk >> 3, nt = blk & 7;
    const size_t Mb = (size_t)mt * 256;
    const int Nb = nt * 256;
    const int wm = w >> 2, wn = w & 3;
    const int ir = l >> 3, s2 = (l & 7) ^ ir;
    const int lm = l & 15, lg4 = l >> 4;

    char* buf0 = smem;
    char* buf1 = smem + 65536;

    auto issueA = [&](int kt, int rep0, char* buf) {
#pragma unroll
        for (int rr = 0; rr < 2; ++rr) {
            int c2 = w * 4 + rep0 + rr;               // 0..31
            gl16(pbuf + (Mb + c2 * 8 + ir) * 768 + kt * 64 + s2 * 8, buf + c2 * 1024);
        }
    };
    auto issueB = [&](int kt, int rep0, char* buf) {
#pragma unroll
        for (int rr = 0; rr < 2; ++rr) {
            int c2 = w * 4 + rep0 + rr;
            gl16(wsL + (size_t)(Nb + c2 * 8 + ir) * 768 + kt * 64 + s2 * 8,
                 buf + 32768 + c2 * 1024);
        }
    };

    f32x4 acc[8][4];
#pragma unroll
    for (int m = 0; m < 8; ++m)
#pragma unroll
        for (int nb = 0; nb < 4; ++nb) acc[m][nb] = (f32x4)0.f;

    // prologue: tile0 fully + tile1 A-pair1; leave pair(1,0) in flight
    issueA(0, 0, buf0); issueA(0, 2, buf0); issueB(0, 0, buf0); issueB(0, 2, buf0);
    issueA(1, 0, buf1);
    VW2(); BAR();

    bf16x8 areg[4][2], breg[4][2];

#pragma unroll 2
    for (int kt = 0; kt < 12; ++kt) {
        char* cur = (kt & 1) ? buf1 : buf0;
        char* nxt = (kt & 1) ? buf0 : buf1;

        // ---- Q00: read a(mh0), b(nh0); issue A-pair2(kt+1); MFMA m0-3 x n0-1 ----
#pragma unroll
        for (int m = 0; m < 4; ++m)
#pragma unroll
            for (int ks = 0; ks < 2; ++ks) {
                int r = wm * 128 + m * 16 + lm, slot = ks * 4 + lg4;
                areg[m][ks] = *(const bf16x8*)(cur + r * 128 + ((slot ^ (r & 7)) << 4));
            }
#pragma unroll
        for (int nb = 0; nb < 2; ++nb)
#pragma unroll
            for (int ks = 0; ks < 2; ++ks) {
                int rb = wn * 64 + nb * 16 + lm, slot = ks * 4 + lg4;
                breg[nb][ks] = *(const bf16x8*)(cur + 32768 + rb * 128 + ((slot ^ (rb & 7)) << 4));
            }
        if (kt < 11) issueA(kt + 1, 2, nxt);
        BAR();
        __builtin_amdgcn_s_setprio(1);
#pragma unroll
        for (int m = 0; m < 4; ++m)
#pragma unroll
            for (int nb = 0; nb < 2; ++nb)
#pragma unroll
                for (int ks = 0; ks < 2; ++ks)
                    acc[m][nb] = __builtin_amdgcn_mfma_f32_16x16x32_bf16(areg[m][ks], breg[nb][ks], acc[m][nb], 0, 0, 0);
        __builtin_amdgcn_s_setprio(0);
        BAR();

        // ---- Q01: read b(nh1); issue B-pair1(kt+1); MFMA m0-3 x n2-3 ----
#pragma unroll
        for (int nb = 2; nb < 4; ++nb)
#pragma unroll
            for (int ks = 0; ks < 2; ++ks) {
                int rb = wn * 64 + nb * 16 + lm, slot = ks * 4 + lg4;
                breg[nb][ks] = *(const bf16x8*)(cur + 32768 + rb * 128 + ((slot ^ (rb & 7)) << 4));
            }
        if (kt < 11) issueB(kt + 1, 0, nxt);
        BAR();
        __builtin_amdgcn_s_setprio(1);
#pragma unroll
        for (int m = 0; m < 4; ++m)
#pragma unroll
            for (int nb = 2; nb < 4; ++nb)
#pragma unroll
                for (int ks = 0; ks < 2; ++ks)
                    acc[m][nb] = __builtin_amdgcn_mfma_f32_16x16x32_bf16(areg[m][ks], breg[nb][ks], acc[m][nb], 0, 0, 0);
        __builtin_amdgcn_s_setprio(0);
        BAR();

        // ---- Q11: read a(mh1); issue B-pair2(kt+1); MFMA m4-7 x n2-3 ----
#pragma unroll
        for (int m = 0; m < 4; ++m)
#pragma unroll
            for (int ks = 0; ks < 2; ++ks) {
                int r = wm * 128 + 64 + m * 16 + lm, slot = ks * 4 + lg4;
                areg[m][ks] = *(const bf16x8*)(cur + r * 128 + ((slot ^ (r & 7)) << 4));
            }
        if (kt < 11) issueB(kt + 1, 2, nxt);
        BAR();
        __builtin_amdgcn_s_setprio(1);
#pragma unroll
        for (int m = 0; m < 4; ++m)
#pragma unroll
            for (int nb = 2; nb < 4; ++nb)
#pragma unroll
                for (int ks = 0; ks < 2; ++ks)
                    acc[4 + m][nb] = __builtin_amdgcn_mfma_f32_16x16x32_bf16(areg[m][ks], breg[nb][ks], acc[4 + m][nb], 0, 0, 0);
        __builtin_amdgcn_s_setprio(0);
        BAR();

        // ---- Q10: issue A-pair1(kt+2) into cur; MFMA m4-7 x n0-1; counted vmcnt ----
        if (kt < 10) issueA(kt + 2, 0, cur);
        __builtin_amdgcn_s_setprio(1);
#pragma unroll
        for (int m = 0; m < 4; ++m)
#pragma unroll
            for (int nb = 0; nb < 2; ++nb)
#pragma unroll
                for (int ks = 0; ks < 2; ++ks)
                    acc[4 + m][nb] = __builtin_amdgcn_mfma_f32_16x16x32_bf16(areg[m][ks], breg[nb][ks], acc[4 + m][nb], 0, 0, 0);
        __builtin_amdgcn_s_setprio(0);
        if (kt < 10) { VW2(); } else { VW0(); }
        BAR();
    }

    // epilogue: exp(2*cos*rpn) with batch lo/hi split (boundary is 16-aligned)
    int b0 = (int)(Mb / 576);
    int brl = (b0 + 1) * 576 - (int)Mb;
    double slo = 0.0, shi = 0.0;
#pragma unroll
    for (int m = 0; m < 8; ++m) {
        int rl = wm * 128 + m * 16;
        float rv[4];
#pragma unroll
        for (int j = 0; j < 4; ++j) rv[j] = rpn[Mb + rl + lg4 * 4 + j];
        float es = 0.f;
#pragma unroll
        for (int nb = 0; nb < 4; ++nb)
#pragma unroll
            for (int j = 0; j < 4; ++j)
                es += __expf(2.0f * acc[m][nb][j] * rv[j]);
        if (rl < brl) slo += (double)es; else shi += (double)es;
    }
#pragma unroll
    for (int off = 32; off; off >>= 1) {
        slo += __shfl_down(slo, off);
        shi += __shfl_down(shi, off);
    }
    __syncthreads();
    double* red = (double*)smem;
    if (l == 0) { red[w * 2] = slo; red[w * 2 + 1] = shi; }
    __syncthreads();
    if (t == 0) {
        double lo = 0.0, hi = 0.0;
#pragma unroll
        for (int i = 0; i < 8; ++i) { lo += red[i * 2]; hi += red[i * 2 + 1]; }
        partials[blk * 2]     = lo;
        partials[blk * 2 + 1] = hi;
    }
}

// ---------------- finish: per-batch gather (<=4 tiles each), log-ratio, mean --------
__global__ void pcl_finish(const double* __restrict__ partials, float* __restrict__ out) {
    int b = threadIdx.x;   // 64 batches
    int mt0 = (b * 576) / 256;
    int mt1 = (b * 576 + 575) / 256;
    double far = 0.0, close = 0.0;
    for (int mt = mt0; mt <= mt1; ++mt) {
        int tb0 = (mt * 256) / 576;
        int off = (tb0 == b) ? 0 : ((tb0 + 1 == b) ? 1 : -1);
        if (off < 0) continue;
        for (int nTile = 0; nTile < 8; ++nTile) {
            double v = partials[(mt * 8 + nTile) * 2 + off];
            if (nTile < 4) far += v; else close += v;
        }
    }
    double lb = log(far) - log(close);
#pragma unroll
    for (int off = 32; off; off >>= 1) lb += __shfl_down(lb, off);
    if (b == 0) out[0] = (float)(lb * (1.0 / 64.0));
}

extern "C" void kernel_launch(void* const* d_in, const int* in_sizes, int n_in,
                              void* d_out, int out_size, void* d_ws, size_t ws_size,
                              hipStream_t stream) {
    const float* x    = (const float*)d_in[0];
    const float* w    = (const float*)d_in[1];
    const float* bias = (const float*)d_in[2];
    const float* l1   = (const float*)d_in[3];
    const float* l2   = (const float*)d_in[4];
    float* out = (float*)d_out;

    unsigned short* xp  = (unsigned short*)d_ws;                        // 36864*768 bf16 (reused as P)
    unsigned short* wsW = (unsigned short*)((char*)d_ws + 56623104);    // 768*768 bf16
    unsigned short* wsL = (unsigned short*)((char*)d_ws + 57802752);    // 2048*768 bf16
    float* rpn          = (float*)((char*)d_ws + 60948480);             // 36864 f32
    double* partials    = (double*)((char*)d_ws + 61095936);            // 1152*2 f64

    (void)hipFuncSetAttribute((const void*)pcl_k1,
                              hipFuncAttributeMaxDynamicSharedMemorySize, K1_LDS);
    (void)hipFuncSetAttribute((const void*)pcl_k2,
                              hipFuncAttributeMaxDynamicSharedMemorySize, K2_LDS);

    pcl_prep_x<<<9216, 256, 0, stream>>>(x, xp);
    pcl_prep_wl<<<2816, 64, 0, stream>>>(w, l1, l2, wsW, wsL);
    pcl_k1<<<576, 512, K1_LDS, stream>>>(xp, wsW, bias, xp, rpn);
    pcl_k2<<<1152, 512, K2_LDS, stream>>>(xp, wsL, rpn, partials);
    pcl_finish<<<1, 64, 0, stream>>>(partials, out);
}

// Round 7
// 245.590 us; speedup vs baseline: 1.5621x; 1.0237x over previous
//
#include <hip/hip_runtime.h>
#include <math.h>

using f32x4  = __attribute__((ext_vector_type(4))) float;
using bf16x8 = __attribute__((ext_vector_type(8))) short;

typedef const __attribute__((address_space(1))) void gas_void;
typedef __attribute__((address_space(3))) void las_void;

__device__ __forceinline__ void gl16(const void* g, void* l) {
    __builtin_amdgcn_global_load_lds((gas_void*)g, (las_void*)l, 16, 0, 0);
}

__device__ __forceinline__ unsigned short f2bf(float f) {
    union { float f; unsigned u; } v; v.f = f;
    unsigned r = v.u + 0x7fffu + ((v.u >> 16) & 1u);   // RNE
    return (unsigned short)(r >> 16);
}
__device__ __forceinline__ float bf2f(unsigned short u) {
    return __uint_as_float(((unsigned)u) << 16);
}

#define VW2() asm volatile("s_waitcnt vmcnt(2)")
#define VW0() asm volatile("s_waitcnt vmcnt(0)")
#define BAR() __builtin_amdgcn_s_barrier()

// ---------------- prep: X (NCHW fp32) -> patch-major bf16 Xp[36864][768] ----------------
__global__ void pcl_prep_x(const float* __restrict__ x, unsigned short* __restrict__ xp) {
    int t = threadIdx.x;              // 256
    int wv = t >> 6, l = t & 63;
    int p = blockIdx.x * 4 + wv;      // patch id
    int b = p / 576, n = p % 576;
    int ph = n / 24, pw = n % 24;
    const float* base = x + ((size_t)(b * 3)) * 147456 + (ph * 16) * 384 + pw * 16;
    unsigned* dst = (unsigned*)(xp + (size_t)p * 768);
#pragma unroll
    for (int q = 0; q < 6; ++q) {
        int k = q * 128 + l * 2;
        int c = k >> 8, i = (k >> 4) & 15, j = k & 15;
        const float* s = base + (size_t)c * 147456 + i * 384 + j;
        float2 v = *(const float2*)s;
        unsigned lo = f2bf(v.x), hi = f2bf(v.y);
        dst[q * 64 + l] = lo | (hi << 16);
    }
}

// ---------------- prep: W -> bf16; latents -> row-normalized bf16 ----------------
__global__ void pcl_prep_wl(const float* __restrict__ w,
                            const float* __restrict__ l1, const float* __restrict__ l2,
                            unsigned short* __restrict__ wsW,
                            unsigned short* __restrict__ wsL) {
    int r = blockIdx.x, t = threadIdx.x;   // 2816 x 64
    if (r < 768) {
        const float* src = w + (size_t)r * 768;
        unsigned short* dst = wsW + (size_t)r * 768;
#pragma unroll
        for (int i = 0; i < 12; ++i) dst[t + 64 * i] = f2bf(src[t + 64 * i]);
    } else {
        int lr = r - 768;
        const float* src = (lr < 1024) ? l1 + (size_t)lr * 768 : l2 + (size_t)(lr - 1024) * 768;
        unsigned short* dst = wsL + (size_t)lr * 768;
        float vals[12];
        float s = 0.f;
#pragma unroll
        for (int i = 0; i < 12; ++i) {
            float f = bf2f(f2bf(src[t + 64 * i]));
            vals[i] = f; s += f * f;
        }
#pragma unroll
        for (int off = 32; off; off >>= 1) s += __shfl_xor(s, off, 64);
        float rn = 1.0f / sqrtf(s);
#pragma unroll
        for (int i = 0; i < 12; ++i) dst[t + 64 * i] = f2bf(vals[i] * rn);
    }
}

// ================= K1: conv GEMM, 1024 thr (16 waves = 4/SIMD), M=64 x N=768 ==========
// wave grid 2(M)x8(N), wave tile 32x96; writes P over xp (block-exclusive rows), rpn.
// LDS: A0 8K @0 | A1 8K @8192 | B 96K @16384 | nrm [64][8]f32 @114688
#define K1_LDS 116736

__global__ __launch_bounds__(1024, 4)
void pcl_k1(const unsigned short* __restrict__ xp,
            const unsigned short* __restrict__ wsW,
            const float* __restrict__ bias,
            unsigned short* __restrict__ pbuf,      // == xp region (safe in-place)
            float* __restrict__ rpn) {
    extern __shared__ char smem[];
    char* A0 = smem; char* A1 = smem + 8192; char* BB = smem + 16384;
    float* nrm = (float*)(smem + 114688);           // [64][8]
    const int t = threadIdx.x, w = t >> 6, l = t & 63;
    const int wm = w >> 3, wn = w & 7;
    const size_t Mb = (size_t)blockIdx.x * 64;
    const int ir = l >> 3, s2 = (l & 7) ^ ir;
    const int lm = l & 15, lg4 = l >> 4;

    f32x4 acc[2][6];
#pragma unroll
    for (int m = 0; m < 2; ++m)
#pragma unroll
        for (int nf = 0; nf < 6; ++nf) acc[m][nf] = (f32x4)0.f;

    if (w < 8) gl16(xp + (Mb + w * 8 + ir) * 768 + s2 * 8, A0 + w * 1024);

    for (int kc = 0; kc < 12; ++kc) {
        __syncthreads();
#pragma unroll
        for (int rep = 0; rep < 6; ++rep) {
            int c2 = w * 6 + rep;                     // 0..95
            gl16(wsW + (size_t)(c2 * 8 + ir) * 768 + kc * 64 + s2 * 8, BB + c2 * 1024);
        }
        if (kc < 11 && w < 8)
            gl16(xp + (Mb + w * 8 + ir) * 768 + (kc + 1) * 64 + s2 * 8,
                 ((kc & 1) ? A0 : A1) + w * 1024);
        __syncthreads();

        const char* A = (kc & 1) ? A1 : A0;
        bf16x8 a[2][2];
#pragma unroll
        for (int m = 0; m < 2; ++m)
#pragma unroll
            for (int ks = 0; ks < 2; ++ks) {
                int r = wm * 32 + m * 16 + lm, slot = ks * 4 + lg4;
                a[m][ks] = *(const bf16x8*)(A + r * 128 + ((slot ^ (r & 7)) << 4));
            }
#pragma unroll
        for (int nf = 0; nf < 6; ++nf) {
            int rb = wn * 96 + nf * 16 + lm;
#pragma unroll
            for (int ks = 0; ks < 2; ++ks) {
                int slot = ks * 4 + lg4;
                bf16x8 bb = *(const bf16x8*)(BB + rb * 128 + ((slot ^ (rb & 7)) << 4));
#pragma unroll
                for (int m = 0; m < 2; ++m)
                    acc[m][nf] = __builtin_amdgcn_mfma_f32_16x16x32_bf16(a[m][ks], bb, acc[m][nf], 0, 0, 0);
            }
        }
    }

    // epilogue: bias add, bf16 P write (in-place), row sum-of-squares from bf16 P
    float rs[2][4];
#pragma unroll
    for (int m = 0; m < 2; ++m)
#pragma unroll
        for (int j = 0; j < 4; ++j) rs[m][j] = 0.f;
#pragma unroll
    for (int nf = 0; nf < 6; ++nf) {
        int d = wn * 96 + nf * 16 + lm;
        float bv = bias[d];
#pragma unroll
        for (int m = 0; m < 2; ++m)
#pragma unroll
            for (int j = 0; j < 4; ++j) {
                int r = wm * 32 + m * 16 + lg4 * 4 + j;
                unsigned short h = f2bf(acc[m][nf][j] + bv);
                pbuf[(Mb + r) * 768 + d] = h;
                float fv = bf2f(h);
                rs[m][j] += fv * fv;
            }
    }
#pragma unroll
    for (int m = 0; m < 2; ++m)
#pragma unroll
        for (int j = 0; j < 4; ++j) {
            rs[m][j] += __shfl_xor(rs[m][j], 1);
            rs[m][j] += __shfl_xor(rs[m][j], 2);
            rs[m][j] += __shfl_xor(rs[m][j], 4);
            rs[m][j] += __shfl_xor(rs[m][j], 8);
        }
    if (lm == 0) {
#pragma unroll
        for (int m = 0; m < 2; ++m)
#pragma unroll
            for (int j = 0; j < 4; ++j)
                nrm[(wm * 32 + m * 16 + lg4 * 4 + j) * 8 + wn] = rs[m][j];
    }
    __syncthreads();
    if (t < 64) {
        float s = 0.f;
#pragma unroll
        for (int i = 0; i < 8; ++i) s += nrm[t * 8 + i];
        rpn[Mb + t] = 1.0f / sqrtf(s);
    }
}

// ================= K2: score GEMM 256x256, 8-phase + counted vmcnt + XCD swizzle ======
// grid 1152; work id wg = (bid%8)*144 + bid/8 -> each XCD owns 18 mt x 8 nt (P L2-reuse)
// LDS: buf0 {A 32K | B 32K} @0 | buf1 @65536  = 128 KiB
#define K2_LDS 131072

__global__ __launch_bounds__(512, 1)
void pcl_k2(const unsigned short* __restrict__ pbuf,
            const unsigned short* __restrict__ wsL,
            const float* __restrict__ rpn,
            double* __restrict__ partials) {
    extern __shared__ char smem[];
    const int t = threadIdx.x, w = t >> 6, l = t & 63;
    const int wg = (blockIdx.x & 7) * 144 + (blockIdx.x >> 3);   // bijective XCD remap
    const int mt = wg >> 3, nt = wg & 7;
    const size_t Mb = (size_t)mt * 256;
    const int Nb = nt * 256;
    const int wm = w >> 2, wn = w & 3;
    const int ir = l >> 3, s2 = (l & 7) ^ ir;
    const int lm = l & 15, lg4 = l >> 4;

    char* buf0 = smem;
    char* buf1 = smem + 65536;

    auto issueA = [&](int kt, int rep0, char* buf) {
#pragma unroll
        for (int rr = 0; rr < 2; ++rr) {
            int c2 = w * 4 + rep0 + rr;               // 0..31
            gl16(pbuf + (Mb + c2 * 8 + ir) * 768 + kt * 64 + s2 * 8, buf + c2 * 1024);
        }
    };
    auto issueB = [&](int kt, int rep0, char* buf) {
#pragma unroll
        for (int rr = 0; rr < 2; ++rr) {
            int c2 = w * 4 + rep0 + rr;
            gl16(wsL + (size_t)(Nb + c2 * 8 + ir) * 768 + kt * 64 + s2 * 8,
                 buf + 32768 + c2 * 1024);
        }
    };

    f32x4 acc[8][4];
#pragma unroll
    for (int m = 0; m < 8; ++m)
#pragma unroll
        for (int nb = 0; nb < 4; ++nb) acc[m][nb] = (f32x4)0.f;

    // prologue: tile0 fully + tile1 A-pair1; leave pair(1,0) in flight
    issueA(0, 0, buf0); issueA(0, 2, buf0); issueB(0, 0, buf0); issueB(0, 2, buf0);
    issueA(1, 0, buf1);
    VW2(); BAR();

    bf16x8 areg[4][2], breg[4][2];

#pragma unroll 2
    for (int kt = 0; kt < 12; ++kt) {
        char* cur = (kt & 1) ? buf1 : buf0;
        char* nxt = (kt & 1) ? buf0 : buf1;

        // ---- Q00: read a(mh0), b(nh0); issue A-pair2(kt+1); MFMA m0-3 x n0-1 ----
#pragma unroll
        for (int m = 0; m < 4; ++m)
#pragma unroll
            for (int ks = 0; ks < 2; ++ks) {
                int r = wm * 128 + m * 16 + lm, slot = ks * 4 + lg4;
                areg[m][ks] = *(const bf16x8*)(cur + r * 128 + ((slot ^ (r & 7)) << 4));
            }
#pragma unroll
        for (int nb = 0; nb < 2; ++nb)
#pragma unroll
            for (int ks = 0; ks < 2; ++ks) {
                int rb = wn * 64 + nb * 16 + lm, slot = ks * 4 + lg4;
                breg[nb][ks] = *(const bf16x8*)(cur + 32768 + rb * 128 + ((slot ^ (rb & 7)) << 4));
            }
        if (kt < 11) issueA(kt + 1, 2, nxt);
        BAR();
        __builtin_amdgcn_s_setprio(1);
#pragma unroll
        for (int m = 0; m < 4; ++m)
#pragma unroll
            for (int nb = 0; nb < 2; ++nb)
#pragma unroll
                for (int ks = 0; ks < 2; ++ks)
                    acc[m][nb] = __builtin_amdgcn_mfma_f32_16x16x32_bf16(areg[m][ks], breg[nb][ks], acc[m][nb], 0, 0, 0);
        __builtin_amdgcn_s_setprio(0);
        BAR();

        // ---- Q01: read b(nh1); issue B-pair1(kt+1); MFMA m0-3 x n2-3 ----
#pragma unroll
        for (int nb = 2; nb < 4; ++nb)
#pragma unroll
            for (int ks = 0; ks < 2; ++ks) {
                int rb = wn * 64 + nb * 16 + lm, slot = ks * 4 + lg4;
                breg[nb][ks] = *(const bf16x8*)(cur + 32768 + rb * 128 + ((slot ^ (rb & 7)) << 4));
            }
        if (kt < 11) issueB(kt + 1, 0, nxt);
        BAR();
        __builtin_amdgcn_s_setprio(1);
#pragma unroll
        for (int m = 0; m < 4; ++m)
#pragma unroll
            for (int nb = 2; nb < 4; ++nb)
#pragma unroll
                for (int ks = 0; ks < 2; ++ks)
                    acc[m][nb] = __builtin_amdgcn_mfma_f32_16x16x32_bf16(areg[m][ks], breg[nb][ks], acc[m][nb], 0, 0, 0);
        __builtin_amdgcn_s_setprio(0);
        BAR();

        // ---- Q11: read a(mh1); issue B-pair2(kt+1); MFMA m4-7 x n2-3 ----
#pragma unroll
        for (int m = 0; m < 4; ++m)
#pragma unroll
            for (int ks = 0; ks < 2; ++ks) {
                int r = wm * 128 + 64 + m * 16 + lm, slot = ks * 4 + lg4;
                areg[m][ks] = *(const bf16x8*)(cur + r * 128 + ((slot ^ (r & 7)) << 4));
            }
        if (kt < 11) issueB(kt + 1, 2, nxt);
        BAR();
        __builtin_amdgcn_s_setprio(1);
#pragma unroll
        for (int m = 0; m < 4; ++m)
#pragma unroll
            for (int nb = 2; nb < 4; ++nb)
#pragma unroll
                for (int ks = 0; ks < 2; ++ks)
                    acc[4 + m][nb] = __builtin_amdgcn_mfma_f32_16x16x32_bf16(areg[m][ks], breg[nb][ks], acc[4 + m][nb], 0, 0, 0);
        __builtin_amdgcn_s_setprio(0);
        BAR();

        // ---- Q10: issue A-pair1(kt+2) into cur; MFMA m4-7 x n0-1; counted vmcnt ----
        if (kt < 10) issueA(kt + 2, 0, cur);
        __builtin_amdgcn_s_setprio(1);
#pragma unroll
        for (int m = 0; m < 4; ++m)
#pragma unroll
            for (int nb = 0; nb < 2; ++nb)
#pragma unroll
                for (int ks = 0; ks < 2; ++ks)
                    acc[4 + m][nb] = __builtin_amdgcn_mfma_f32_16x16x32_bf16(areg[m][ks], breg[nb][ks], acc[4 + m][nb], 0, 0, 0);
        __builtin_amdgcn_s_setprio(0);
        if (kt < 10) { VW2(); } else { VW0(); }
        BAR();
    }

    // epilogue: exp(2*cos*rpn) with batch lo/hi split (boundary is 16-aligned)
    int b0 = (int)(Mb / 576);
    int brl = (b0 + 1) * 576 - (int)Mb;
    double slo = 0.0, shi = 0.0;
#pragma unroll
    for (int m = 0; m < 8; ++m) {
        int rl = wm * 128 + m * 16;
        float rv[4];
#pragma unroll
        for (int j = 0; j < 4; ++j) rv[j] = rpn[Mb + rl + lg4 * 4 + j];
        float es = 0.f;
#pragma unroll
        for (int nb = 0; nb < 4; ++nb)
#pragma unroll
            for (int j = 0; j < 4; ++j)
                es += __expf(2.0f * acc[m][nb][j] * rv[j]);
        if (rl < brl) slo += (double)es; else shi += (double)es;
    }
#pragma unroll
    for (int off = 32; off; off >>= 1) {
        slo += __shfl_down(slo, off);
        shi += __shfl_down(shi, off);
    }
    __syncthreads();
    double* red = (double*)smem;
    if (l == 0) { red[w * 2] = slo; red[w * 2 + 1] = shi; }
    __syncthreads();
    if (t == 0) {
        double lo = 0.0, hi = 0.0;
#pragma unroll
        for (int i = 0; i < 8; ++i) { lo += red[i * 2]; hi += red[i * 2 + 1]; }
        partials[wg * 2]     = lo;
        partials[wg * 2 + 1] = hi;
    }
}

// ---------------- finish: per-batch gather (<=4 tiles each), log-ratio, mean --------
__global__ void pcl_finish(const double* __restrict__ partials, float* __restrict__ out) {
    int b = threadIdx.x;   // 64 batches
    int mt0 = (b * 576) / 256;
    int mt1 = (b * 576 + 575) / 256;
    double far = 0.0, close = 0.0;
    for (int mt = mt0; mt <= mt1; ++mt) {
        int tb0 = (mt * 256) / 576;
        int off = (tb0 == b) ? 0 : ((tb0 + 1 == b) ? 1 : -1);
        if (off < 0) continue;
        for (int nTile = 0; nTile < 8; ++nTile) {
            double v = partials[(mt * 8 + nTile) * 2 + off];
            if (nTile < 4) far += v; else close += v;
        }
    }
    double lb = log(far) - log(close);
#pragma unroll
    for (int off = 32; off; off >>= 1) lb += __shfl_down(lb, off);
    if (b == 0) out[0] = (float)(lb * (1.0 / 64.0));
}

extern "C" void kernel_launch(void* const* d_in, const int* in_sizes, int n_in,
                              void* d_out, int out_size, void* d_ws, size_t ws_size,
                              hipStream_t stream) {
    const float* x    = (const float*)d_in[0];
    const float* w    = (const float*)d_in[1];
    const float* bias = (const float*)d_in[2];
    const float* l1   = (const float*)d_in[3];
    const float* l2   = (const float*)d_in[4];
    float* out = (float*)d_out;

    unsigned short* xp  = (unsigned short*)d_ws;                        // 36864*768 bf16 (reused as P)
    unsigned short* wsW = (unsigned short*)((char*)d_ws + 56623104);    // 768*768 bf16
    unsigned short* wsL = (unsigned short*)((char*)d_ws + 57802752);    // 2048*768 bf16
    float* rpn          = (float*)((char*)d_ws + 60948480);             // 36864 f32
    double* partials    = (double*)((char*)d_ws + 61095936);            // 1152*2 f64

    (void)hipFuncSetAttribute((const void*)pcl_k1,
                              hipFuncAttributeMaxDynamicSharedMemorySize, K1_LDS);
    (void)hipFuncSetAttribute((const void*)pcl_k2,
                              hipFuncAttributeMaxDynamicSharedMemorySize, K2_LDS);

    pcl_prep_x<<<9216, 256, 0, stream>>>(x, xp);
    pcl_prep_wl<<<2816, 64, 0, stream>>>(w, l1, l2, wsW, wsL);
    pcl_k1<<<576, 1024, K1_LDS, stream>>>(xp, wsW, bias, xp, rpn);
    pcl_k2<<<1152, 512, K2_LDS, stream>>>(xp, wsL, rpn, partials);
    pcl_finish<<<1, 64, 0, stream>>>(partials, out);
}

// Round 8
// 238.659 us; speedup vs baseline: 1.6075x; 1.0290x over previous
//
#include <hip/hip_runtime.h>
#include <math.h>

using f32x4  = __attribute__((ext_vector_type(4))) float;
using bf16x8 = __attribute__((ext_vector_type(8))) short;

typedef const __attribute__((address_space(1))) void gas_void;
typedef __attribute__((address_space(3))) void las_void;

__device__ __forceinline__ void gl16(const void* g, void* l) {
    __builtin_amdgcn_global_load_lds((gas_void*)g, (las_void*)l, 16, 0, 0);
}

__device__ __forceinline__ unsigned short f2bf(float f) {
    union { float f; unsigned u; } v; v.f = f;
    unsigned r = v.u + 0x7fffu + ((v.u >> 16) & 1u);   // RNE
    return (unsigned short)(r >> 16);
}
__device__ __forceinline__ float bf2f(unsigned short u) {
    return __uint_as_float(((unsigned)u) << 16);
}

#define VW3() asm volatile("s_waitcnt vmcnt(3)")
#define VW0() asm volatile("s_waitcnt vmcnt(0)")
#define BAR() __builtin_amdgcn_s_barrier()

// ---------------- prep: X (NCHW fp32) -> patch-major bf16 Xp[36864][768] ----------------
__global__ void pcl_prep_x(const float* __restrict__ x, unsigned short* __restrict__ xp) {
    int t = threadIdx.x;              // 256
    int wv = t >> 6, l = t & 63;
    int p = blockIdx.x * 4 + wv;      // patch id
    int b = p / 576, n = p % 576;
    int ph = n / 24, pw = n % 24;
    const float* base = x + ((size_t)(b * 3)) * 147456 + (ph * 16) * 384 + pw * 16;
    unsigned* dst = (unsigned*)(xp + (size_t)p * 768);
#pragma unroll
    for (int q = 0; q < 6; ++q) {
        int k = q * 128 + l * 2;
        int c = k >> 8, i = (k >> 4) & 15, j = k & 15;
        const float* s = base + (size_t)c * 147456 + i * 384 + j;
        float2 v = *(const float2*)s;
        unsigned lo = f2bf(v.x), hi = f2bf(v.y);
        dst[q * 64 + l] = lo | (hi << 16);
    }
}

// ---------------- prep: W -> bf16; latents -> row-normalized bf16 ----------------
__global__ void pcl_prep_wl(const float* __restrict__ w,
                            const float* __restrict__ l1, const float* __restrict__ l2,
                            unsigned short* __restrict__ wsW,
                            unsigned short* __restrict__ wsL) {
    int r = blockIdx.x, t = threadIdx.x;   // 2816 x 64
    if (r < 768) {
        const float* src = w + (size_t)r * 768;
        unsigned short* dst = wsW + (size_t)r * 768;
#pragma unroll
        for (int i = 0; i < 12; ++i) dst[t + 64 * i] = f2bf(src[t + 64 * i]);
    } else {
        int lr = r - 768;
        const float* src = (lr < 1024) ? l1 + (size_t)lr * 768 : l2 + (size_t)(lr - 1024) * 768;
        unsigned short* dst = wsL + (size_t)lr * 768;
        float vals[12];
        float s = 0.f;
#pragma unroll
        for (int i = 0; i < 12; ++i) {
            float f = bf2f(f2bf(src[t + 64 * i]));
            vals[i] = f; s += f * f;
        }
#pragma unroll
        for (int off = 32; off; off >>= 1) s += __shfl_xor(s, off, 64);
        float rn = 1.0f / sqrtf(s);
#pragma unroll
        for (int i = 0; i < 12; ++i) dst[t + 64 * i] = f2bf(vals[i] * rn);
    }
}

// ================= K1: conv GEMM, 1024 thr (16 waves), M=64 x N=768 (R7-proven) ========
// LDS: A0 8K @0 | A1 8K @8192 | B 96K @16384 | nrm [64][8]f32 @114688
#define K1_LDS 116736

__global__ __launch_bounds__(1024, 4)
void pcl_k1(const unsigned short* __restrict__ xp,
            const unsigned short* __restrict__ wsW,
            const float* __restrict__ bias,
            unsigned short* __restrict__ pbuf,      // == xp region (safe in-place)
            float* __restrict__ rpn) {
    extern __shared__ char smem[];
    char* A0 = smem; char* A1 = smem + 8192; char* BB = smem + 16384;
    float* nrm = (float*)(smem + 114688);           // [64][8]
    const int t = threadIdx.x, w = t >> 6, l = t & 63;
    const int wm = w >> 3, wn = w & 7;
    const size_t Mb = (size_t)blockIdx.x * 64;
    const int ir = l >> 3, s2 = (l & 7) ^ ir;
    const int lm = l & 15, lg4 = l >> 4;

    f32x4 acc[2][6];
#pragma unroll
    for (int m = 0; m < 2; ++m)
#pragma unroll
        for (int nf = 0; nf < 6; ++nf) acc[m][nf] = (f32x4)0.f;

    if (w < 8) gl16(xp + (Mb + w * 8 + ir) * 768 + s2 * 8, A0 + w * 1024);

    for (int kc = 0; kc < 12; ++kc) {
        __syncthreads();
#pragma unroll
        for (int rep = 0; rep < 6; ++rep) {
            int c2 = w * 6 + rep;                     // 0..95
            gl16(wsW + (size_t)(c2 * 8 + ir) * 768 + kc * 64 + s2 * 8, BB + c2 * 1024);
        }
        if (kc < 11 && w < 8)
            gl16(xp + (Mb + w * 8 + ir) * 768 + (kc + 1) * 64 + s2 * 8,
                 ((kc & 1) ? A0 : A1) + w * 1024);
        __syncthreads();

        const char* A = (kc & 1) ? A1 : A0;
        bf16x8 a[2][2];
#pragma unroll
        for (int m = 0; m < 2; ++m)
#pragma unroll
            for (int ks = 0; ks < 2; ++ks) {
                int r = wm * 32 + m * 16 + lm, slot = ks * 4 + lg4;
                a[m][ks] = *(const bf16x8*)(A + r * 128 + ((slot ^ (r & 7)) << 4));
            }
#pragma unroll
        for (int nf = 0; nf < 6; ++nf) {
            int rb = wn * 96 + nf * 16 + lm;
#pragma unroll
            for (int ks = 0; ks < 2; ++ks) {
                int slot = ks * 4 + lg4;
                bf16x8 bb = *(const bf16x8*)(BB + rb * 128 + ((slot ^ (rb & 7)) << 4));
#pragma unroll
                for (int m = 0; m < 2; ++m)
                    acc[m][nf] = __builtin_amdgcn_mfma_f32_16x16x32_bf16(a[m][ks], bb, acc[m][nf], 0, 0, 0);
            }
        }
    }

    // epilogue: bias add, bf16 P write (in-place), row sum-of-squares from bf16 P
    float rs[2][4];
#pragma unroll
    for (int m = 0; m < 2; ++m)
#pragma unroll
        for (int j = 0; j < 4; ++j) rs[m][j] = 0.f;
#pragma unroll
    for (int nf = 0; nf < 6; ++nf) {
        int d = wn * 96 + nf * 16 + lm;
        float bv = bias[d];
#pragma unroll
        for (int m = 0; m < 2; ++m)
#pragma unroll
            for (int j = 0; j < 4; ++j) {
                int r = wm * 32 + m * 16 + lg4 * 4 + j;
                unsigned short h = f2bf(acc[m][nf][j] + bv);
                pbuf[(Mb + r) * 768 + d] = h;
                float fv = bf2f(h);
                rs[m][j] += fv * fv;
            }
    }
#pragma unroll
    for (int m = 0; m < 2; ++m)
#pragma unroll
        for (int j = 0; j < 4; ++j) {
            rs[m][j] += __shfl_xor(rs[m][j], 1);
            rs[m][j] += __shfl_xor(rs[m][j], 2);
            rs[m][j] += __shfl_xor(rs[m][j], 4);
            rs[m][j] += __shfl_xor(rs[m][j], 8);
        }
    if (lm == 0) {
#pragma unroll
        for (int m = 0; m < 2; ++m)
#pragma unroll
            for (int j = 0; j < 4; ++j)
                nrm[(wm * 32 + m * 16 + lg4 * 4 + j) * 8 + wn] = rs[m][j];
    }
    __syncthreads();
    if (t < 64) {
        float s = 0.f;
#pragma unroll
        for (int i = 0; i < 8; ++i) s += nrm[t * 8 + i];
        rpn[Mb + t] = 1.0f / sqrtf(s);
    }
}

// ================= K2: score GEMM 192x256 tiles, 8-phase, deep vmcnt ledger ===========
// grid 1536 = 192 mt x 8 nt = exactly 6 blocks/CU; XCD remap; 8 waves 2(M)x4(N),
// wave tile 96x64. LDS per buf: A 24K | B 32K = 56K; two bufs = 112K.
// Ledger: entering tile kt, in-flight = A(kt+1)x3. Phases issue B1(kt+1)2 / B2(kt+1)2 /
// - / A(kt+2)3; boundary vmcnt(3) drains exactly tile kt+1.
#define K2_LDS 114688

__global__ __launch_bounds__(512, 1)
void pcl_k2(const unsigned short* __restrict__ pbuf,
            const unsigned short* __restrict__ wsL,
            const float* __restrict__ rpn,
            double* __restrict__ partials) {
    extern __shared__ char smem[];
    const int t = threadIdx.x, w = t >> 6, l = t & 63;
    const int wg = (blockIdx.x & 7) * 192 + (blockIdx.x >> 3);   // bijective XCD remap
    const int mt = wg >> 3, nt = wg & 7;
    const size_t Mb = (size_t)mt * 192;
    const int Nb = nt * 256;
    const int wm = w >> 2, wn = w & 3;
    const int ir = l >> 3, s2 = (l & 7) ^ ir;
    const int lm = l & 15, lg4 = l >> 4;

    char* buf0 = smem;
    char* buf1 = smem + 57344;

    auto issueA = [&](int kt, char* buf) {          // 3 chunks: rows Mb..Mb+191
#pragma unroll
        for (int rr = 0; rr < 3; ++rr) {
            int c2 = w * 3 + rr;                    // 0..23
            gl16(pbuf + (Mb + c2 * 8 + ir) * 768 + kt * 64 + s2 * 8, buf + c2 * 1024);
        }
    };
    auto issueB = [&](int kt, int rep0, char* buf) { // 2 chunks each half
#pragma unroll
        for (int rr = 0; rr < 2; ++rr) {
            int c2 = w * 4 + rep0 + rr;             // 0..31
            gl16(wsL + (size_t)(Nb + c2 * 8 + ir) * 768 + kt * 64 + s2 * 8,
                 buf + 24576 + c2 * 1024);
        }
    };

    f32x4 acc[6][4];
#pragma unroll
    for (int m = 0; m < 6; ++m)
#pragma unroll
        for (int nb = 0; nb < 4; ++nb) acc[m][nb] = (f32x4)0.f;

    // prologue: tile0 (A3+B4) + A(1)x3; vmcnt(3) -> tile0 landed, A(1) in flight
    issueA(0, buf0); issueB(0, 0, buf0); issueB(0, 2, buf0);
    issueA(1, buf1);
    VW3(); BAR();

    bf16x8 areg[3][2], breg[4][2];

#pragma unroll 2
    for (int kt = 0; kt < 12; ++kt) {
        char* cur = (kt & 1) ? buf1 : buf0;
        char* nxt = (kt & 1) ? buf0 : buf1;

        // ---- Q00: read a(mh0) 6 + b(nh0) 4; issue B1(kt+1); MFMA mh0 x nh0 (12) ----
#pragma unroll
        for (int m = 0; m < 3; ++m)
#pragma unroll
            for (int ks = 0; ks < 2; ++ks) {
                int r = wm * 96 + m * 16 + lm, slot = ks * 4 + lg4;
                areg[m][ks] = *(const bf16x8*)(cur + r * 128 + ((slot ^ (r & 7)) << 4));
            }
#pragma unroll
        for (int nb = 0; nb < 2; ++nb)
#pragma unroll
            for (int ks = 0; ks < 2; ++ks) {
                int rb = wn * 64 + nb * 16 + lm, slot = ks * 4 + lg4;
                breg[nb][ks] = *(const bf16x8*)(cur + 24576 + rb * 128 + ((slot ^ (rb & 7)) << 4));
            }
        if (kt < 11) issueB(kt + 1, 0, nxt);
        BAR();
        __builtin_amdgcn_s_setprio(1);
#pragma unroll
        for (int m = 0; m < 3; ++m)
#pragma unroll
            for (int nb = 0; nb < 2; ++nb)
#pragma unroll
                for (int ks = 0; ks < 2; ++ks)
                    acc[m][nb] = __builtin_amdgcn_mfma_f32_16x16x32_bf16(areg[m][ks], breg[nb][ks], acc[m][nb], 0, 0, 0);
        __builtin_amdgcn_s_setprio(0);
        BAR();

        // ---- Q01: read b(nh1) 4; issue B2(kt+1); MFMA mh0 x nh1 (12) ----
#pragma unroll
        for (int nb = 2; nb < 4; ++nb)
#pragma unroll
            for (int ks = 0; ks < 2; ++ks) {
                int rb = wn * 64 + nb * 16 + lm, slot = ks * 4 + lg4;
                breg[nb][ks] = *(const bf16x8*)(cur + 24576 + rb * 128 + ((slot ^ (rb & 7)) << 4));
            }
        if (kt < 11) issueB(kt + 1, 2, nxt);
        BAR();
        __builtin_amdgcn_s_setprio(1);
#pragma unroll
        for (int m = 0; m < 3; ++m)
#pragma unroll
            for (int nb = 2; nb < 4; ++nb)
#pragma unroll
                for (int ks = 0; ks < 2; ++ks)
                    acc[m][nb] = __builtin_amdgcn_mfma_f32_16x16x32_bf16(areg[m][ks], breg[nb][ks], acc[m][nb], 0, 0, 0);
        __builtin_amdgcn_s_setprio(0);
        BAR();

        // ---- Q11: read a(mh1) 6; MFMA mh1 x nh1 (12) ----
#pragma unroll
        for (int m = 0; m < 3; ++m)
#pragma unroll
            for (int ks = 0; ks < 2; ++ks) {
                int r = wm * 96 + 48 + m * 16 + lm, slot = ks * 4 + lg4;
                areg[m][ks] = *(const bf16x8*)(cur + r * 128 + ((slot ^ (r & 7)) << 4));
            }
        BAR();
        __builtin_amdgcn_s_setprio(1);
#pragma unroll
        for (int m = 0; m < 3; ++m)
#pragma unroll
            for (int nb = 2; nb < 4; ++nb)
#pragma unroll
                for (int ks = 0; ks < 2; ++ks)
                    acc[3 + m][nb] = __builtin_amdgcn_mfma_f32_16x16x32_bf16(areg[m][ks], breg[nb][ks], acc[3 + m][nb], 0, 0, 0);
        __builtin_amdgcn_s_setprio(0);
        BAR();

        // ---- Q10: issue A(kt+2) into cur-A (reads of cur-A done); MFMA mh1 x nh0 ----
        if (kt < 10) issueA(kt + 2, cur);
        __builtin_amdgcn_s_setprio(1);
#pragma unroll
        for (int m = 0; m < 3; ++m)
#pragma unroll
            for (int nb = 0; nb < 2; ++nb)
#pragma unroll
                for (int ks = 0; ks < 2; ++ks)
                    acc[3 + m][nb] = __builtin_amdgcn_mfma_f32_16x16x32_bf16(areg[m][ks], breg[nb][ks], acc[3 + m][nb], 0, 0, 0);
        __builtin_amdgcn_s_setprio(0);
        if (kt < 10) { VW3(); } else { VW0(); }
        BAR();
    }

    // epilogue: exp(2*cos*rpn); whole tile lies in one batch (192 | 576)
    double ssum = 0.0;
#pragma unroll
    for (int m = 0; m < 6; ++m) {
        int mh = m / 3, mi = m % 3;
        int rl = wm * 96 + mh * 48 + mi * 16;
        float rv[4];
#pragma unroll
        for (int j = 0; j < 4; ++j) rv[j] = rpn[Mb + rl + lg4 * 4 + j];
        float es = 0.f;
#pragma unroll
        for (int nb = 0; nb < 4; ++nb)
#pragma unroll
            for (int j = 0; j < 4; ++j)
                es += __expf(2.0f * acc[m][nb][j] * rv[j]);
        ssum += (double)es;
    }
#pragma unroll
    for (int off = 32; off; off >>= 1) ssum += __shfl_down(ssum, off);
    __syncthreads();
    double* red = (double*)smem;
    if (l == 0) red[w] = ssum;
    __syncthreads();
    if (t == 0) {
        double s = 0.0;
#pragma unroll
        for (int i = 0; i < 8; ++i) s += red[i];
        partials[wg] = s;
    }
}

// ---------------- finish: per-batch gather (3 mt x 8 nt), log-ratio, mean --------
__global__ void pcl_finish(const double* __restrict__ partials, float* __restrict__ out) {
    int b = threadIdx.x;   // 64 batches
    double far = 0.0, close = 0.0;
#pragma unroll
    for (int i = 0; i < 3; ++i) {
        int mt = b * 3 + i;
#pragma unroll
        for (int nTile = 0; nTile < 8; ++nTile) {
            double v = partials[mt * 8 + nTile];
            if (nTile < 4) far += v; else close += v;
        }
    }
    double lb = log(far) - log(close);
#pragma unroll
    for (int off = 32; off; off >>= 1) lb += __shfl_down(lb, off);
    if (b == 0) out[0] = (float)(lb * (1.0 / 64.0));
}

extern "C" void kernel_launch(void* const* d_in, const int* in_sizes, int n_in,
                              void* d_out, int out_size, void* d_ws, size_t ws_size,
                              hipStream_t stream) {
    const float* x    = (const float*)d_in[0];
    const float* w    = (const float*)d_in[1];
    const float* bias = (const float*)d_in[2];
    const float* l1   = (const float*)d_in[3];
    const float* l2   = (const float*)d_in[4];
    float* out = (float*)d_out;

    unsigned short* xp  = (unsigned short*)d_ws;                        // 36864*768 bf16 (reused as P)
    unsigned short* wsW = (unsigned short*)((char*)d_ws + 56623104);    // 768*768 bf16
    unsigned short* wsL = (unsigned short*)((char*)d_ws + 57802752);    // 2048*768 bf16
    float* rpn          = (float*)((char*)d_ws + 60948480);             // 36864 f32
    double* partials    = (double*)((char*)d_ws + 61095936);            // 1536 f64

    (void)hipFuncSetAttribute((const void*)pcl_k1,
                              hipFuncAttributeMaxDynamicSharedMemorySize, K1_LDS);
    (void)hipFuncSetAttribute((const void*)pcl_k2,
                              hipFuncAttributeMaxDynamicSharedMemorySize, K2_LDS);

    pcl_prep_x<<<9216, 256, 0, stream>>>(x, xp);
    pcl_prep_wl<<<2816, 64, 0, stream>>>(w, l1, l2, wsW, wsL);
    pcl_k1<<<576, 1024, K1_LDS, stream>>>(xp, wsW, bias, xp, rpn);
    pcl_k2<<<1536, 512, K2_LDS, stream>>>(xp, wsL, rpn, partials);
    pcl_finish<<<1, 64, 0, stream>>>(partials, out);
}

// Round 9
// 232.867 us; speedup vs baseline: 1.6475x; 1.0249x over previous
//
#include <hip/hip_runtime.h>
#include <math.h>

using f32x4  = __attribute__((ext_vector_type(4))) float;
using bf16x8 = __attribute__((ext_vector_type(8))) short;

typedef const __attribute__((address_space(1))) void gas_void;
typedef __attribute__((address_space(3))) void las_void;

__device__ __forceinline__ void gl16(const void* g, void* l) {
    __builtin_amdgcn_global_load_lds((gas_void*)g, (las_void*)l, 16, 0, 0);
}

__device__ __forceinline__ unsigned short f2bf(float f) {
    union { float f; unsigned u; } v; v.f = f;
    unsigned r = v.u + 0x7fffu + ((v.u >> 16) & 1u);   // RNE
    return (unsigned short)(r >> 16);
}
__device__ __forceinline__ float bf2f(unsigned short u) {
    return __uint_as_float(((unsigned)u) << 16);
}

#define VW6() asm volatile("s_waitcnt vmcnt(6)")
#define VW0() asm volatile("s_waitcnt vmcnt(0)")
#define BAR() __builtin_amdgcn_s_barrier()

// ---------------- prep: X (NCHW fp32) -> patch-major bf16 Xp[36864][768] ----------------
__global__ void pcl_prep_x(const float* __restrict__ x, unsigned short* __restrict__ xp) {
    int t = threadIdx.x;              // 256
    int wv = t >> 6, l = t & 63;
    int p = blockIdx.x * 4 + wv;      // patch id
    int b = p / 576, n = p % 576;
    int ph = n / 24, pw = n % 24;
    const float* base = x + ((size_t)(b * 3)) * 147456 + (ph * 16) * 384 + pw * 16;
    unsigned* dst = (unsigned*)(xp + (size_t)p * 768);
#pragma unroll
    for (int q = 0; q < 6; ++q) {
        int k = q * 128 + l * 2;
        int c = k >> 8, i = (k >> 4) & 15, j = k & 15;
        const float* s = base + (size_t)c * 147456 + i * 384 + j;
        float2 v = *(const float2*)s;
        unsigned lo = f2bf(v.x), hi = f2bf(v.y);
        dst[q * 64 + l] = lo | (hi << 16);
    }
}

// ---------------- prep: W -> bf16; latents -> row-normalized bf16 ----------------
__global__ void pcl_prep_wl(const float* __restrict__ w,
                            const float* __restrict__ l1, const float* __restrict__ l2,
                            unsigned short* __restrict__ wsW,
                            unsigned short* __restrict__ wsL) {
    int r = blockIdx.x, t = threadIdx.x;   // 2816 x 64
    if (r < 768) {
        const float* src = w + (size_t)r * 768;
        unsigned short* dst = wsW + (size_t)r * 768;
#pragma unroll
        for (int i = 0; i < 12; ++i) dst[t + 64 * i] = f2bf(src[t + 64 * i]);
    } else {
        int lr = r - 768;
        const float* src = (lr < 1024) ? l1 + (size_t)lr * 768 : l2 + (size_t)(lr - 1024) * 768;
        unsigned short* dst = wsL + (size_t)lr * 768;
        float vals[12];
        float s = 0.f;
#pragma unroll
        for (int i = 0; i < 12; ++i) {
            float f = bf2f(f2bf(src[t + 64 * i]));
            vals[i] = f; s += f * f;
        }
#pragma unroll
        for (int off = 32; off; off >>= 1) s += __shfl_xor(s, off, 64);
        float rn = 1.0f / sqrtf(s);
#pragma unroll
        for (int i = 0; i < 12; ++i) dst[t + 64 * i] = f2bf(vals[i] * rn);
    }
}

// ================= K1: conv GEMM, 1024 thr (16 waves), M=64 x N=768 (R7-proven) ========
// LDS: A0 8K @0 | A1 8K @8192 | B 96K @16384 | nrm [64][8]f32 @114688
#define K1_LDS 116736

__global__ __launch_bounds__(1024, 4)
void pcl_k1(const unsigned short* __restrict__ xp,
            const unsigned short* __restrict__ wsW,
            const float* __restrict__ bias,
            unsigned short* __restrict__ pbuf,      // == xp region (safe in-place)
            float* __restrict__ rpn) {
    extern __shared__ char smem[];
    char* A0 = smem; char* A1 = smem + 8192; char* BB = smem + 16384;
    float* nrm = (float*)(smem + 114688);           // [64][8]
    const int t = threadIdx.x, w = t >> 6, l = t & 63;
    const int wm = w >> 3, wn = w & 7;
    const size_t Mb = (size_t)blockIdx.x * 64;
    const int ir = l >> 3, s2 = (l & 7) ^ ir;
    const int lm = l & 15, lg4 = l >> 4;

    f32x4 acc[2][6];
#pragma unroll
    for (int m = 0; m < 2; ++m)
#pragma unroll
        for (int nf = 0; nf < 6; ++nf) acc[m][nf] = (f32x4)0.f;

    if (w < 8) gl16(xp + (Mb + w * 8 + ir) * 768 + s2 * 8, A0 + w * 1024);

    for (int kc = 0; kc < 12; ++kc) {
        __syncthreads();
#pragma unroll
        for (int rep = 0; rep < 6; ++rep) {
            int c2 = w * 6 + rep;                     // 0..95
            gl16(wsW + (size_t)(c2 * 8 + ir) * 768 + kc * 64 + s2 * 8, BB + c2 * 1024);
        }
        if (kc < 11 && w < 8)
            gl16(xp + (Mb + w * 8 + ir) * 768 + (kc + 1) * 64 + s2 * 8,
                 ((kc & 1) ? A0 : A1) + w * 1024);
        __syncthreads();

        const char* A = (kc & 1) ? A1 : A0;
        bf16x8 a[2][2];
#pragma unroll
        for (int m = 0; m < 2; ++m)
#pragma unroll
            for (int ks = 0; ks < 2; ++ks) {
                int r = wm * 32 + m * 16 + lm, slot = ks * 4 + lg4;
                a[m][ks] = *(const bf16x8*)(A + r * 128 + ((slot ^ (r & 7)) << 4));
            }
#pragma unroll
        for (int nf = 0; nf < 6; ++nf) {
            int rb = wn * 96 + nf * 16 + lm;
#pragma unroll
            for (int ks = 0; ks < 2; ++ks) {
                int slot = ks * 4 + lg4;
                bf16x8 bb = *(const bf16x8*)(BB + rb * 128 + ((slot ^ (rb & 7)) << 4));
#pragma unroll
                for (int m = 0; m < 2; ++m)
                    acc[m][nf] = __builtin_amdgcn_mfma_f32_16x16x32_bf16(a[m][ks], bb, acc[m][nf], 0, 0, 0);
            }
        }
    }

    // epilogue: bias add, bf16 P write (in-place), row sum-of-squares from bf16 P
    float rs[2][4];
#pragma unroll
    for (int m = 0; m < 2; ++m)
#pragma unroll
        for (int j = 0; j < 4; ++j) rs[m][j] = 0.f;
#pragma unroll
    for (int nf = 0; nf < 6; ++nf) {
        int d = wn * 96 + nf * 16 + lm;
        float bv = bias[d];
#pragma unroll
        for (int m = 0; m < 2; ++m)
#pragma unroll
            for (int j = 0; j < 4; ++j) {
                int r = wm * 32 + m * 16 + lg4 * 4 + j;
                unsigned short h = f2bf(acc[m][nf][j] + bv);
                pbuf[(Mb + r) * 768 + d] = h;
                float fv = bf2f(h);
                rs[m][j] += fv * fv;
            }
    }
#pragma unroll
    for (int m = 0; m < 2; ++m)
#pragma unroll
        for (int j = 0; j < 4; ++j) {
            rs[m][j] += __shfl_xor(rs[m][j], 1);
            rs[m][j] += __shfl_xor(rs[m][j], 2);
            rs[m][j] += __shfl_xor(rs[m][j], 4);
            rs[m][j] += __shfl_xor(rs[m][j], 8);
        }
    if (lm == 0) {
#pragma unroll
        for (int m = 0; m < 2; ++m)
#pragma unroll
            for (int j = 0; j < 4; ++j)
                nrm[(wm * 32 + m * 16 + lg4 * 4 + j) * 8 + wn] = rs[m][j];
    }
    __syncthreads();
    if (t < 64) {
        float s = 0.f;
#pragma unroll
        for (int i = 0; i < 8; ++i) s += nrm[t * 8 + i];
        rpn[Mb + t] = 1.0f / sqrtf(s);
    }
}

// ================= K2: score GEMM 192x128 tiles, 256 thr, 2 blocks/CU ================
// grid 3072 = 192 mt x 16 nt = 12 blocks/CU exact; XCD remap; 4 waves 2(M)x2(N),
// wave tile 96x64 (inner loop identical to R8). LDS per buf: A 24K | B 16K = 40K;
// two bufs = 80K -> 2 blocks/CU -> cross-block pipe overlap (MFMA vs LDS/stage).
// Ledger: entering kt, in-flight = A(kt+1)x6. Q00 +B1(2), Q01 +B2(2), Q10 +A(kt+2)(6),
// then vmcnt(6) drains exactly tile kt+1. Tail kt>=10: vmcnt(0).
#define K2_LDS 81920

__global__ __launch_bounds__(256, 2)
void pcl_k2(const unsigned short* __restrict__ pbuf,
            const unsigned short* __restrict__ wsL,
            const float* __restrict__ rpn,
            double* __restrict__ partials) {
    extern __shared__ char smem[];
    const int t = threadIdx.x, w = t >> 6, l = t & 63;
    const int wg = (blockIdx.x & 7) * 384 + (blockIdx.x >> 3);   // bijective XCD remap
    const int mt = wg >> 4, nt = wg & 15;
    const size_t Mb = (size_t)mt * 192;
    const int Nb = nt * 128;
    const int wm = w >> 1, wn = w & 1;
    const int ir = l >> 3, s2 = (l & 7) ^ ir;
    const int lm = l & 15, lg4 = l >> 4;

    char* buf0 = smem;
    char* buf1 = smem + 40960;

    auto issueA = [&](int kt, char* buf) {          // 6 chunks/wave: rows Mb..Mb+191
#pragma unroll
        for (int rr = 0; rr < 6; ++rr) {
            int c2 = w * 6 + rr;                    // 0..23
            gl16(pbuf + (Mb + c2 * 8 + ir) * 768 + kt * 64 + s2 * 8, buf + c2 * 1024);
        }
    };
    auto issueB = [&](int kt, int rep0, char* buf) { // 2 chunks/wave each half
#pragma unroll
        for (int rr = 0; rr < 2; ++rr) {
            int c2 = w * 4 + rep0 + rr;             // 0..15
            gl16(wsL + (size_t)(Nb + c2 * 8 + ir) * 768 + kt * 64 + s2 * 8,
                 buf + 24576 + c2 * 1024);
        }
    };

    f32x4 acc[6][4];
#pragma unroll
    for (int m = 0; m < 6; ++m)
#pragma unroll
        for (int nb = 0; nb < 4; ++nb) acc[m][nb] = (f32x4)0.f;

    // prologue: tile0 (A6+B4) + A(1)x6; vmcnt(6) -> tile0 landed, A(1) in flight
    issueA(0, buf0); issueB(0, 0, buf0); issueB(0, 2, buf0);
    issueA(1, buf1);
    VW6(); BAR();

    bf16x8 areg[3][2], breg[4][2];

#pragma unroll 2
    for (int kt = 0; kt < 12; ++kt) {
        char* cur = (kt & 1) ? buf1 : buf0;
        char* nxt = (kt & 1) ? buf0 : buf1;

        // ---- Q00: read a(mh0) 6 + b(nh0) 4; issue B1(kt+1); MFMA mh0 x nh0 (12) ----
#pragma unroll
        for (int m = 0; m < 3; ++m)
#pragma unroll
            for (int ks = 0; ks < 2; ++ks) {
                int r = wm * 96 + m * 16 + lm, slot = ks * 4 + lg4;
                areg[m][ks] = *(const bf16x8*)(cur + r * 128 + ((slot ^ (r & 7)) << 4));
            }
#pragma unroll
        for (int nb = 0; nb < 2; ++nb)
#pragma unroll
            for (int ks = 0; ks < 2; ++ks) {
                int rb = wn * 64 + nb * 16 + lm, slot = ks * 4 + lg4;
                breg[nb][ks] = *(const bf16x8*)(cur + 24576 + rb * 128 + ((slot ^ (rb & 7)) << 4));
            }
        if (kt < 11) issueB(kt + 1, 0, nxt);
        BAR();
        __builtin_amdgcn_s_setprio(1);
#pragma unroll
        for (int m = 0; m < 3; ++m)
#pragma unroll
            for (int nb = 0; nb < 2; ++nb)
#pragma unroll
                for (int ks = 0; ks < 2; ++ks)
                    acc[m][nb] = __builtin_amdgcn_mfma_f32_16x16x32_bf16(areg[m][ks], breg[nb][ks], acc[m][nb], 0, 0, 0);
        __builtin_amdgcn_s_setprio(0);
        BAR();

        // ---- Q01: read b(nh1) 4; issue B2(kt+1); MFMA mh0 x nh1 (12) ----
#pragma unroll
        for (int nb = 2; nb < 4; ++nb)
#pragma unroll
            for (int ks = 0; ks < 2; ++ks) {
                int rb = wn * 64 + nb * 16 + lm, slot = ks * 4 + lg4;
                breg[nb][ks] = *(const bf16x8*)(cur + 24576 + rb * 128 + ((slot ^ (rb & 7)) << 4));
            }
        if (kt < 11) issueB(kt + 1, 2, nxt);
        BAR();
        __builtin_amdgcn_s_setprio(1);
#pragma unroll
        for (int m = 0; m < 3; ++m)
#pragma unroll
            for (int nb = 2; nb < 4; ++nb)
#pragma unroll
                for (int ks = 0; ks < 2; ++ks)
                    acc[m][nb] = __builtin_amdgcn_mfma_f32_16x16x32_bf16(areg[m][ks], breg[nb][ks], acc[m][nb], 0, 0, 0);
        __builtin_amdgcn_s_setprio(0);
        BAR();

        // ---- Q11: read a(mh1) 6; MFMA mh1 x nh1 (12) ----
#pragma unroll
        for (int m = 0; m < 3; ++m)
#pragma unroll
            for (int ks = 0; ks < 2; ++ks) {
                int r = wm * 96 + 48 + m * 16 + lm, slot = ks * 4 + lg4;
                areg[m][ks] = *(const bf16x8*)(cur + r * 128 + ((slot ^ (r & 7)) << 4));
            }
        BAR();
        __builtin_amdgcn_s_setprio(1);
#pragma unroll
        for (int m = 0; m < 3; ++m)
#pragma unroll
            for (int nb = 2; nb < 4; ++nb)
#pragma unroll
                for (int ks = 0; ks < 2; ++ks)
                    acc[3 + m][nb] = __builtin_amdgcn_mfma_f32_16x16x32_bf16(areg[m][ks], breg[nb][ks], acc[3 + m][nb], 0, 0, 0);
        __builtin_amdgcn_s_setprio(0);
        BAR();

        // ---- Q10: issue A(kt+2) into cur-A (reads of cur-A done); MFMA mh1 x nh0 ----
        if (kt < 10) issueA(kt + 2, cur);
        __builtin_amdgcn_s_setprio(1);
#pragma unroll
        for (int m = 0; m < 3; ++m)
#pragma unroll
            for (int nb = 0; nb < 2; ++nb)
#pragma unroll
                for (int ks = 0; ks < 2; ++ks)
                    acc[3 + m][nb] = __builtin_amdgcn_mfma_f32_16x16x32_bf16(areg[m][ks], breg[nb][ks], acc[3 + m][nb], 0, 0, 0);
        __builtin_amdgcn_s_setprio(0);
        if (kt < 10) { VW6(); } else { VW0(); }
        BAR();
    }

    // epilogue: exp(2*cos*rpn); whole tile lies in one batch (192 | 576)
    double ssum = 0.0;
#pragma unroll
    for (int m = 0; m < 6; ++m) {
        int mh = m / 3, mi = m % 3;
        int rl = wm * 96 + mh * 48 + mi * 16;
        float rv[4];
#pragma unroll
        for (int j = 0; j < 4; ++j) rv[j] = rpn[Mb + rl + lg4 * 4 + j];
        float es = 0.f;
#pragma unroll
        for (int nb = 0; nb < 4; ++nb)
#pragma unroll
            for (int j = 0; j < 4; ++j)
                es += __expf(2.0f * acc[m][nb][j] * rv[j]);
        ssum += (double)es;
    }
#pragma unroll
    for (int off = 32; off; off >>= 1) ssum += __shfl_down(ssum, off);
    __syncthreads();
    double* red = (double*)smem;
    if (l == 0) red[w] = ssum;
    __syncthreads();
    if (t == 0) {
        double s = 0.0;
#pragma unroll
        for (int i = 0; i < 4; ++i) s += red[i];
        partials[wg] = s;
    }
}

// ---------------- finish: per-batch gather (3 mt x 16 nt), log-ratio, mean --------
__global__ void pcl_finish(const double* __restrict__ partials, float* __restrict__ out) {
    int b = threadIdx.x;   // 64 batches
    double far = 0.0, close = 0.0;
#pragma unroll
    for (int i = 0; i < 3; ++i) {
        int mt = b * 3 + i;
#pragma unroll
        for (int nTile = 0; nTile < 16; ++nTile) {
            double v = partials[mt * 16 + nTile];
            if (nTile < 8) far += v; else close += v;
        }
    }
    double lb = log(far) - log(close);
#pragma unroll
    for (int off = 32; off; off >>= 1) lb += __shfl_down(lb, off);
    if (b == 0) out[0] = (float)(lb * (1.0 / 64.0));
}

extern "C" void kernel_launch(void* const* d_in, const int* in_sizes, int n_in,
                              void* d_out, int out_size, void* d_ws, size_t ws_size,
                              hipStream_t stream) {
    const float* x    = (const float*)d_in[0];
    const float* w    = (const float*)d_in[1];
    const float* bias = (const float*)d_in[2];
    const float* l1   = (const float*)d_in[3];
    const float* l2   = (const float*)d_in[4];
    float* out = (float*)d_out;

    unsigned short* xp  = (unsigned short*)d_ws;                        // 36864*768 bf16 (reused as P)
    unsigned short* wsW = (unsigned short*)((char*)d_ws + 56623104);    // 768*768 bf16
    unsigned short* wsL = (unsigned short*)((char*)d_ws + 57802752);    // 2048*768 bf16
    float* rpn          = (float*)((char*)d_ws + 60948480);             // 36864 f32
    double* partials    = (double*)((char*)d_ws + 61095936);            // 3072 f64

    (void)hipFuncSetAttribute((const void*)pcl_k1,
                              hipFuncAttributeMaxDynamicSharedMemorySize, K1_LDS);
    (void)hipFuncSetAttribute((const void*)pcl_k2,
                              hipFuncAttributeMaxDynamicSharedMemorySize, K2_LDS);

    pcl_prep_x<<<9216, 256, 0, stream>>>(x, xp);
    pcl_prep_wl<<<2816, 64, 0, stream>>>(w, l1, l2, wsW, wsL);
    pcl_k1<<<576, 1024, K1_LDS, stream>>>(xp, wsW, bias, xp, rpn);
    pcl_k2<<<3072, 256, K2_LDS, stream>>>(xp, wsL, rpn, partials);
    pcl_finish<<<1, 64, 0, stream>>>(partials, out);
}

// Round 10
// 216.806 us; speedup vs baseline: 1.7695x; 1.0741x over previous
//
#include <hip/hip_runtime.h>
#include <math.h>

using f32x4  = __attribute__((ext_vector_type(4))) float;
using bf16x8 = __attribute__((ext_vector_type(8))) short;

typedef const __attribute__((address_space(1))) void gas_void;
typedef __attribute__((address_space(3))) void las_void;

__device__ __forceinline__ void gl16(const void* g, void* l) {
    __builtin_amdgcn_global_load_lds((gas_void*)g, (las_void*)l, 16, 0, 0);
}

__device__ __forceinline__ unsigned short f2bf(float f) {
    union { float f; unsigned u; } v; v.f = f;
    unsigned r = v.u + 0x7fffu + ((v.u >> 16) & 1u);   // RNE
    return (unsigned short)(r >> 16);
}
__device__ __forceinline__ float bf2f(unsigned short u) {
    return __uint_as_float(((unsigned)u) << 16);
}

#define VW0() asm volatile("s_waitcnt vmcnt(0)")
#define BAR() __builtin_amdgcn_s_barrier()

// ---------------- prep: W -> bf16; latents -> row-normalized bf16 ----------------
__global__ void pcl_prep_wl(const float* __restrict__ w,
                            const float* __restrict__ l1, const float* __restrict__ l2,
                            unsigned short* __restrict__ wsW,
                            unsigned short* __restrict__ wsL) {
    int r = blockIdx.x, t = threadIdx.x;   // 2816 x 64
    if (r < 768) {
        const float* src = w + (size_t)r * 768;
        unsigned short* dst = wsW + (size_t)r * 768;
#pragma unroll
        for (int i = 0; i < 12; ++i) dst[t + 64 * i] = f2bf(src[t + 64 * i]);
    } else {
        int lr = r - 768;
        const float* src = (lr < 1024) ? l1 + (size_t)lr * 768 : l2 + (size_t)(lr - 1024) * 768;
        unsigned short* dst = wsL + (size_t)lr * 768;
        float vals[12];
        float s = 0.f;
#pragma unroll
        for (int i = 0; i < 12; ++i) {
            float f = bf2f(f2bf(src[t + 64 * i]));
            vals[i] = f; s += f * f;
        }
#pragma unroll
        for (int off = 32; off; off >>= 1) s += __shfl_xor(s, off, 64);
        float rn = 1.0f / sqrtf(s);
#pragma unroll
        for (int i = 0; i < 12; ++i) dst[t + 64 * i] = f2bf(vals[i] * rn);
    }
}

// ================= K1: fused X-gather + conv GEMM, 512 thr (8 waves 1Mx8N) ===========
// M=64, N=768; wave tile 64x96. X gathered fp32->bf16 in-register (prefetched one kc
// ahead), A staged via ds_write; B (whole W k-slice, 96KB) via gl16 per kc.
// LDS: A 8K @0 | B 96K @8192 | nrm [64][8]f32 @106496
#define K1_LDS 108544

__global__ __launch_bounds__(512, 1)
void pcl_k1(const float* __restrict__ x,
            const unsigned short* __restrict__ wsW,
            const float* __restrict__ bias,
            unsigned short* __restrict__ pbuf,
            float* __restrict__ rpn) {
    extern __shared__ char smem[];
    char* AA = smem;
    char* BB = smem + 8192;
    float* nrm = (float*)(smem + 106496);           // [64][8]
    const int t = threadIdx.x, w = t >> 6, l = t & 63;
    const size_t Mb = (size_t)blockIdx.x * 64;
    const int ir = l >> 3, s2 = (l & 7) ^ ir;
    const int lm = l & 15, lg4 = l >> 4;

    // X gather ids: row sr (0..63), k-slot ss (0..7); 8 consecutive k per thread
    const int sr = t >> 3, ss = t & 7;
    {
    }
    const int n = (int)Mb + sr;
    const int bb_ = n / 576, n5 = n % 576;
    const int ph = n5 / 24, pw = n5 % 24;
    const float* xbase = x + ((size_t)(bb_ * 3)) * 147456
                       + (size_t)(ph * 16 + (ss >> 1)) * 384 + pw * 16 + (ss & 1) * 8;
    char* aw = AA + sr * 128 + ((ss ^ (sr & 7)) << 4);

    f32x4 acc[4][6];
#pragma unroll
    for (int m = 0; m < 4; ++m)
#pragma unroll
        for (int nf = 0; nf < 6; ++nf) acc[m][nf] = (f32x4)0.f;

    // prologue: load X(0) into regs
    f32x4 xr0, xr1;
    {
        const float* s = xbase;                      // kc=0 offset = 0
        xr0 = *(const f32x4*)s; xr1 = *(const f32x4*)(s + 4);
    }

    for (int kc = 0; kc < 12; ++kc) {
        __syncthreads();   // prev compute done -> B and A writable
        // stage B(kc): whole W k-slice, 96 chunks
#pragma unroll
        for (int rep = 0; rep < 12; ++rep) {
            int c2 = w + 8 * rep;                     // 0..95
            gl16(wsW + (size_t)(c2 * 8 + ir) * 768 + kc * 64 + s2 * 8, BB + c2 * 1024);
        }
        // write A(kc) from regs (bf16 pack, swizzled slot)
        {
            bf16x8 pkt;
#pragma unroll
            for (int j = 0; j < 4; ++j) {
                pkt[j]     = (short)f2bf(xr0[j]);
                pkt[4 + j] = (short)f2bf(xr1[j]);
            }
            *(bf16x8*)aw = pkt;
        }
        __syncthreads();   // gl16 + ds_write drained

        // prefetch X(kc+1) into regs; latency hides under compute
        if (kc < 11) {
            int kn = kc + 1;
            const float* s = xbase + (size_t)(kn >> 2) * 147456 + (kn & 3) * 1536;
            xr0 = *(const f32x4*)s; xr1 = *(const f32x4*)(s + 4);
        }

        // compute: wave w covers cols w*96..w*96+95
        bf16x8 a[4][2];
#pragma unroll
        for (int m = 0; m < 4; ++m)
#pragma unroll
            for (int ks = 0; ks < 2; ++ks) {
                int r = m * 16 + lm, slot = ks * 4 + lg4;
                a[m][ks] = *(const bf16x8*)(AA + r * 128 + ((slot ^ (r & 7)) << 4));
            }
#pragma unroll
        for (int nf = 0; nf < 6; ++nf) {
            int rb = w * 96 + nf * 16 + lm;
#pragma unroll
            for (int ks = 0; ks < 2; ++ks) {
                int slot = ks * 4 + lg4;
                bf16x8 bb = *(const bf16x8*)(BB + rb * 128 + ((slot ^ (rb & 7)) << 4));
#pragma unroll
                for (int m = 0; m < 4; ++m)
                    acc[m][nf] = __builtin_amdgcn_mfma_f32_16x16x32_bf16(a[m][ks], bb, acc[m][nf], 0, 0, 0);
            }
        }
    }

    // epilogue: bias add, bf16 P write, row sum-of-squares from bf16 P
    float rs[4][4];
#pragma unroll
    for (int m = 0; m < 4; ++m)
#pragma unroll
        for (int j = 0; j < 4; ++j) rs[m][j] = 0.f;
#pragma unroll
    for (int nf = 0; nf < 6; ++nf) {
        int d = w * 96 + nf * 16 + lm;
        float bv = bias[d];
#pragma unroll
        for (int m = 0; m < 4; ++m)
#pragma unroll
            for (int j = 0; j < 4; ++j) {
                int r = m * 16 + lg4 * 4 + j;
                unsigned short h = f2bf(acc[m][nf][j] + bv);
                pbuf[(Mb + r) * 768 + d] = h;
                float fv = bf2f(h);
                rs[m][j] += fv * fv;
            }
    }
#pragma unroll
    for (int m = 0; m < 4; ++m)
#pragma unroll
        for (int j = 0; j < 4; ++j) {
            rs[m][j] += __shfl_xor(rs[m][j], 1);
            rs[m][j] += __shfl_xor(rs[m][j], 2);
            rs[m][j] += __shfl_xor(rs[m][j], 4);
            rs[m][j] += __shfl_xor(rs[m][j], 8);
        }
    if (lm == 0) {
#pragma unroll
        for (int m = 0; m < 4; ++m)
#pragma unroll
            for (int j = 0; j < 4; ++j)
                nrm[(m * 16 + lg4 * 4 + j) * 8 + w] = rs[m][j];
    }
    __syncthreads();
    if (t < 64) {
        float s = 0.f;
#pragma unroll
        for (int i = 0; i < 8; ++i) s += nrm[t * 8 + i];
        rpn[Mb + t] = 1.0f / sqrtf(s);
    }
}

// ================= K2: score GEMM 192x128, 2-phase 1-barrier/K-tile, 2 blocks/CU =====
// grid 3072 = 192 mt x 16 nt = 12 blocks/CU; XCD remap; 4 waves 2(M)x2(N), wave 96x64.
// LDS per buf: A 24K | B 16K = 40K; two bufs = 80K -> 2 blocks/CU.
// Per K-tile: issue 10 gl16 (kt+1 -> nxt), read 20 b128, 48 MFMA (no inner barriers,
// compiler lgkmcnt pipelining + wave drift + cross-block overlap), vmcnt(0)+barrier.
#define K2_LDS 81920

__global__ __launch_bounds__(256, 2)
void pcl_k2(const unsigned short* __restrict__ pbuf,
            const unsigned short* __restrict__ wsL,
            const float* __restrict__ rpn,
            double* __restrict__ partials) {
    extern __shared__ char smem[];
    const int t = threadIdx.x, w = t >> 6, l = t & 63;
    const int wg = (blockIdx.x & 7) * 384 + (blockIdx.x >> 3);   // bijective XCD remap
    const int mt = wg >> 4, nt = wg & 15;
    const size_t Mb = (size_t)mt * 192;
    const int Nb = nt * 128;
    const int wm = w >> 1, wn = w & 1;
    const int ir = l >> 3, s2 = (l & 7) ^ ir;
    const int lm = l & 15, lg4 = l >> 4;

    char* buf0 = smem;
    char* buf1 = smem + 40960;

    auto stage = [&](int kt, char* buf) {            // A 6 + B 4 chunks per wave
#pragma unroll
        for (int rr = 0; rr < 6; ++rr) {
            int c2 = w * 6 + rr;                     // 0..23
            gl16(pbuf + (Mb + c2 * 8 + ir) * 768 + kt * 64 + s2 * 8, buf + c2 * 1024);
        }
#pragma unroll
        for (int rr = 0; rr < 4; ++rr) {
            int c2 = w * 4 + rr;                     // 0..15
            gl16(wsL + (size_t)(Nb + c2 * 8 + ir) * 768 + kt * 64 + s2 * 8,
                 buf + 24576 + c2 * 1024);
        }
    };

    f32x4 acc[6][4];
#pragma unroll
    for (int m = 0; m < 6; ++m)
#pragma unroll
        for (int nb = 0; nb < 4; ++nb) acc[m][nb] = (f32x4)0.f;

    stage(0, buf0);
    VW0(); BAR();

    bf16x8 areg[3][2], breg[4][2];

#pragma unroll 2
    for (int kt = 0; kt < 12; ++kt) {
        char* cur = (kt & 1) ? buf1 : buf0;
        char* nxt = (kt & 1) ? buf0 : buf1;

        if (kt < 11) stage(kt + 1, nxt);

        // read b (all 4 n-frags) + a half0; MFMA mh0
#pragma unroll
        for (int nb = 0; nb < 4; ++nb)
#pragma unroll
            for (int ks = 0; ks < 2; ++ks) {
                int rb = wn * 64 + nb * 16 + lm, slot = ks * 4 + lg4;
                breg[nb][ks] = *(const bf16x8*)(cur + 24576 + rb * 128 + ((slot ^ (rb & 7)) << 4));
            }
#pragma unroll
        for (int m = 0; m < 3; ++m)
#pragma unroll
            for (int ks = 0; ks < 2; ++ks) {
                int r = wm * 96 + m * 16 + lm, slot = ks * 4 + lg4;
                areg[m][ks] = *(const bf16x8*)(cur + r * 128 + ((slot ^ (r & 7)) << 4));
            }
        __builtin_amdgcn_s_setprio(1);
#pragma unroll
        for (int m = 0; m < 3; ++m)
#pragma unroll
            for (int nb = 0; nb < 4; ++nb)
#pragma unroll
                for (int ks = 0; ks < 2; ++ks)
                    acc[m][nb] = __builtin_amdgcn_mfma_f32_16x16x32_bf16(areg[m][ks], breg[nb][ks], acc[m][nb], 0, 0, 0);
        __builtin_amdgcn_s_setprio(0);

        // read a half1; MFMA mh1
#pragma unroll
        for (int m = 0; m < 3; ++m)
#pragma unroll
            for (int ks = 0; ks < 2; ++ks) {
                int r = wm * 96 + 48 + m * 16 + lm, slot = ks * 4 + lg4;
                areg[m][ks] = *(const bf16x8*)(cur + r * 128 + ((slot ^ (r & 7)) << 4));
            }
        __builtin_amdgcn_s_setprio(1);
#pragma unroll
        for (int m = 0; m < 3; ++m)
#pragma unroll
            for (int nb = 0; nb < 4; ++nb)
#pragma unroll
                for (int ks = 0; ks < 2; ++ks)
                    acc[3 + m][nb] = __builtin_amdgcn_mfma_f32_16x16x32_bf16(areg[m][ks], breg[nb][ks], acc[3 + m][nb], 0, 0, 0);
        __builtin_amdgcn_s_setprio(0);

        VW0();   // kt+1 fully staged into nxt
        BAR();   // all waves done reading cur -> next iter may overwrite it
    }

    // epilogue: exp(2*cos*rpn); whole tile lies in one batch (192 | 576)
    double ssum = 0.0;
#pragma unroll
    for (int m = 0; m < 6; ++m) {
        int mh = m / 3, mi = m % 3;
        int rl = wm * 96 + mh * 48 + mi * 16;
        float rv[4];
#pragma unroll
        for (int j = 0; j < 4; ++j) rv[j] = rpn[Mb + rl + lg4 * 4 + j];
        float es = 0.f;
#pragma unroll
        for (int nb = 0; nb < 4; ++nb)
#pragma unroll
            for (int j = 0; j < 4; ++j)
                es += __expf(2.0f * acc[m][nb][j] * rv[j]);
        ssum += (double)es;
    }
#pragma unroll
    for (int off = 32; off; off >>= 1) ssum += __shfl_down(ssum, off);
    __syncthreads();
    double* red = (double*)smem;
    if (l == 0) red[w] = ssum;
    __syncthreads();
    if (t == 0) {
        double s = 0.0;
#pragma unroll
        for (int i = 0; i < 4; ++i) s += red[i];
        partials[wg] = s;
    }
}

// ---------------- finish: per-batch gather (3 mt x 16 nt), log-ratio, mean --------
__global__ void pcl_finish(const double* __restrict__ partials, float* __restrict__ out) {
    int b = threadIdx.x;   // 64 batches
    double far = 0.0, close = 0.0;
#pragma unroll
    for (int i = 0; i < 3; ++i) {
        int mt = b * 3 + i;
#pragma unroll
        for (int nTile = 0; nTile < 16; ++nTile) {
            double v = partials[mt * 16 + nTile];
            if (nTile < 8) far += v; else close += v;
        }
    }
    double lb = log(far) - log(close);
#pragma unroll
    for (int off = 32; off; off >>= 1) lb += __shfl_down(lb, off);
    if (b == 0) out[0] = (float)(lb * (1.0 / 64.0));
}

extern "C" void kernel_launch(void* const* d_in, const int* in_sizes, int n_in,
                              void* d_out, int out_size, void* d_ws, size_t ws_size,
                              hipStream_t stream) {
    const float* x    = (const float*)d_in[0];
    const float* w    = (const float*)d_in[1];
    const float* bias = (const float*)d_in[2];
    const float* l1   = (const float*)d_in[3];
    const float* l2   = (const float*)d_in[4];
    float* out = (float*)d_out;

    unsigned short* pbuf = (unsigned short*)d_ws;                       // 36864*768 bf16 P
    unsigned short* wsW  = (unsigned short*)((char*)d_ws + 56623104);   // 768*768 bf16
    unsigned short* wsL  = (unsigned short*)((char*)d_ws + 57802752);   // 2048*768 bf16
    float* rpn           = (float*)((char*)d_ws + 60948480);            // 36864 f32
    double* partials     = (double*)((char*)d_ws + 61095936);           // 3072 f64

    (void)hipFuncSetAttribute((const void*)pcl_k1,
                              hipFuncAttributeMaxDynamicSharedMemorySize, K1_LDS);
    (void)hipFuncSetAttribute((const void*)pcl_k2,
                              hipFuncAttributeMaxDynamicSharedMemorySize, K2_LDS);

    pcl_prep_wl<<<2816, 64, 0, stream>>>(w, l1, l2, wsW, wsL);
    pcl_k1<<<576, 512, K1_LDS, stream>>>(x, wsW, bias, pbuf, rpn);
    pcl_k2<<<3072, 256, K2_LDS, stream>>>(pbuf, wsL, rpn, partials);
    pcl_finish<<<1, 64, 0, stream>>>(partials, out);
}

// Round 11
// 209.950 us; speedup vs baseline: 1.8273x; 1.0327x over previous
//
#include <hip/hip_runtime.h>
#include <math.h>

using f32x4  = __attribute__((ext_vector_type(4))) float;
using bf16x8 = __attribute__((ext_vector_type(8))) short;

typedef const __attribute__((address_space(1))) void gas_void;
typedef __attribute__((address_space(3))) void las_void;

__device__ __forceinline__ void gl16(const void* g, void* l) {
    __builtin_amdgcn_global_load_lds((gas_void*)g, (las_void*)l, 16, 0, 0);
}

__device__ __forceinline__ unsigned short f2bf(float f) {
    union { float f; unsigned u; } v; v.f = f;
    unsigned r = v.u + 0x7fffu + ((v.u >> 16) & 1u);   // RNE
    return (unsigned short)(r >> 16);
}
__device__ __forceinline__ float bf2f(unsigned short u) {
    return __uint_as_float(((unsigned)u) << 16);
}

#define VW0() asm volatile("s_waitcnt vmcnt(0)")
#define VWL0() asm volatile("s_waitcnt vmcnt(0) lgkmcnt(0)")
#define BAR() __builtin_amdgcn_s_barrier()

// ---------------- prep: W -> bf16; latents -> row-normalized bf16 ----------------
__global__ void pcl_prep_wl(const float* __restrict__ w,
                            const float* __restrict__ l1, const float* __restrict__ l2,
                            unsigned short* __restrict__ wsW,
                            unsigned short* __restrict__ wsL) {
    int r = blockIdx.x, t = threadIdx.x;   // 2816 x 64
    if (r < 768) {
        const float* src = w + (size_t)r * 768;
        unsigned short* dst = wsW + (size_t)r * 768;
#pragma unroll
        for (int i = 0; i < 12; ++i) dst[t + 64 * i] = f2bf(src[t + 64 * i]);
    } else {
        int lr = r - 768;
        const float* src = (lr < 1024) ? l1 + (size_t)lr * 768 : l2 + (size_t)(lr - 1024) * 768;
        unsigned short* dst = wsL + (size_t)lr * 768;
        float vals[12];
        float s = 0.f;
#pragma unroll
        for (int i = 0; i < 12; ++i) {
            float f = bf2f(f2bf(src[t + 64 * i]));
            vals[i] = f; s += f * f;
        }
#pragma unroll
        for (int off = 32; off; off >>= 1) s += __shfl_xor(s, off, 64);
        float rn = 1.0f / sqrtf(s);
#pragma unroll
        for (int i = 0; i < 12; ++i) dst[t + 64 * i] = f2bf(vals[i] * rn);
    }
}

// ================= K1: fused X-gather conv GEMM, k2-clone structure =================
// grid 1152 = 192 mt x 6 nt (nt fastest -> XCD shares X panel); 256 thr, 4 waves 2Mx2N,
// wave tile 96x64. LDS per buf: A 24K | B 16K = 40K; x2 = 80K -> 2 blocks/CU.
// B = W-tile via gl16; A = X fp32 loaded to regs at phase top (12 f32x4/thread),
// cvt bf16 + swizzled ds_write after MFMAs (T14). 1 barrier per K-tile.
// Epilogue: bias, bf16 P -> pbuf, per-nt partial row sumsq -> rpnp.
#define K1_LDS 81920

__global__ __launch_bounds__(256, 2)
void pcl_k1(const float* __restrict__ x,
            const unsigned short* __restrict__ wsW,
            const float* __restrict__ bias,
            unsigned short* __restrict__ pbuf,
            float* __restrict__ rpnp) {
    extern __shared__ char smem[];
    const int t = threadIdx.x, w = t >> 6, l = t & 63;
    const int wg = (blockIdx.x & 7) * 144 + (blockIdx.x >> 3);   // bijective XCD remap
    const int mt = wg / 6, nt = wg % 6;
    const size_t Mb = (size_t)mt * 192;
    const int Nb = nt * 128;
    const int wm = w >> 1, wn = w & 1;
    const int ir = l >> 3, s2 = (l & 7) ^ ir;
    const int lm = l & 15, lg4 = l >> 4;

    char* buf0 = smem;
    char* buf1 = smem + 40960;

    // ---- per-thread constant A-staging geometry ----
    const int sl8 = t & 7;                 // k-slot (0..7), constant across reps
    const float* xbase[6];
    int awoff[6];
#pragma unroll
    for (int rep = 0; rep < 6; ++rep) {
        int row = rep * 32 + (t >> 3);     // 0..191
        int n = (int)Mb + row;
        int b = n / 576, n5 = n % 576;
        int ph = n5 / 24, pw = n5 % 24;
        xbase[rep] = x + (size_t)b * 442368 + (size_t)ph * 6144 + pw * 16;
        awoff[rep] = row * 128 + ((sl8 ^ (row & 7)) << 4);
    }
    auto xoff = [&](int kt) {
        int k0 = kt * 64 + sl8 * 8;
        return (k0 >> 8) * 147456 + (((k0 >> 4) & 15)) * 384 + (k0 & 15);
    };

    auto issueB = [&](int kt, char* buf) {
#pragma unroll
        for (int rr = 0; rr < 4; ++rr) {
            int c2 = w * 4 + rr;           // 0..15
            gl16(wsW + (size_t)(Nb + c2 * 8 + ir) * 768 + kt * 64 + s2 * 8,
                 buf + 24576 + c2 * 1024);
        }
    };

    f32x4 xr[6][2];
    auto loadX = [&](int kt) {
        int off = xoff(kt);
#pragma unroll
        for (int rep = 0; rep < 6; ++rep) {
            const float* s = xbase[rep] + off;
            xr[rep][0] = *(const f32x4*)s;
            xr[rep][1] = *(const f32x4*)(s + 4);
        }
    };
    auto writeA = [&](char* buf) {
#pragma unroll
        for (int rep = 0; rep < 6; ++rep) {
            bf16x8 pkt;
#pragma unroll
            for (int j = 0; j < 4; ++j) {
                pkt[j]     = (short)f2bf(xr[rep][0][j]);
                pkt[4 + j] = (short)f2bf(xr[rep][1][j]);
            }
            *(bf16x8*)(buf + awoff[rep]) = pkt;
        }
    };

    f32x4 acc[6][4];
#pragma unroll
    for (int m = 0; m < 6; ++m)
#pragma unroll
        for (int nb = 0; nb < 4; ++nb) acc[m][nb] = (f32x4)0.f;

    // prologue: stage tile0
    loadX(0);
    issueB(0, buf0);
    writeA(buf0);          // compiler waits xr; vmcnt drain below covers gl16
    VWL0(); BAR();

    bf16x8 areg[3][2], breg[4][2];

#pragma unroll 2
    for (int kt = 0; kt < 12; ++kt) {
        char* cur = (kt & 1) ? buf1 : buf0;
        char* nxt = (kt & 1) ? buf0 : buf1;

        if (kt < 11) { loadX(kt + 1); issueB(kt + 1, nxt); }

        // read b (4 n-frags) + a half0; MFMA mh0
#pragma unroll
        for (int nb = 0; nb < 4; ++nb)
#pragma unroll
            for (int ks = 0; ks < 2; ++ks) {
                int rb = wn * 64 + nb * 16 + lm, slot = ks * 4 + lg4;
                breg[nb][ks] = *(const bf16x8*)(cur + 24576 + rb * 128 + ((slot ^ (rb & 7)) << 4));
            }
#pragma unroll
        for (int m = 0; m < 3; ++m)
#pragma unroll
            for (int ks = 0; ks < 2; ++ks) {
                int r = wm * 96 + m * 16 + lm, slot = ks * 4 + lg4;
                areg[m][ks] = *(const bf16x8*)(cur + r * 128 + ((slot ^ (r & 7)) << 4));
            }
        __builtin_amdgcn_s_setprio(1);
#pragma unroll
        for (int m = 0; m < 3; ++m)
#pragma unroll
            for (int nb = 0; nb < 4; ++nb)
#pragma unroll
                for (int ks = 0; ks < 2; ++ks)
                    acc[m][nb] = __builtin_amdgcn_mfma_f32_16x16x32_bf16(areg[m][ks], breg[nb][ks], acc[m][nb], 0, 0, 0);
        __builtin_amdgcn_s_setprio(0);

        // read a half1; MFMA mh1
#pragma unroll
        for (int m = 0; m < 3; ++m)
#pragma unroll
            for (int ks = 0; ks < 2; ++ks) {
                int r = wm * 96 + 48 + m * 16 + lm, slot = ks * 4 + lg4;
                areg[m][ks] = *(const bf16x8*)(cur + r * 128 + ((slot ^ (r & 7)) << 4));
            }
        __builtin_amdgcn_s_setprio(1);
#pragma unroll
        for (int m = 0; m < 3; ++m)
#pragma unroll
            for (int nb = 0; nb < 4; ++nb)
#pragma unroll
                for (int ks = 0; ks < 2; ++ks)
                    acc[3 + m][nb] = __builtin_amdgcn_mfma_f32_16x16x32_bf16(areg[m][ks], breg[nb][ks], acc[3 + m][nb], 0, 0, 0);
        __builtin_amdgcn_s_setprio(0);

        if (kt < 11) writeA(nxt);    // cvt + ds_write next A-tile

        VWL0();  // gl16 landed + ds_writes retired
        BAR();   // all waves done reading cur
    }

    // ---- epilogue: bias, bf16 P store, partial row sumsq over this block's 128 cols ----
    float rs[6][4];
#pragma unroll
    for (int m = 0; m < 6; ++m)
#pragma unroll
        for (int j = 0; j < 4; ++j) rs[m][j] = 0.f;
#pragma unroll
    for (int nb = 0; nb < 4; ++nb) {
        int d = Nb + wn * 64 + nb * 16 + lm;
        float bv = bias[d];
#pragma unroll
        for (int m = 0; m < 6; ++m) {
            int mh = m / 3, mi = m % 3;
#pragma unroll
            for (int j = 0; j < 4; ++j) {
                int row = wm * 96 + mh * 48 + mi * 16 + lg4 * 4 + j;
                unsigned short h = f2bf(acc[m][nb][j] + bv);
                pbuf[(Mb + row) * 768 + d] = h;
                float fv = bf2f(h);
                rs[m][j] += fv * fv;
            }
        }
    }
#pragma unroll
    for (int m = 0; m < 6; ++m)
#pragma unroll
        for (int j = 0; j < 4; ++j) {
            rs[m][j] += __shfl_xor(rs[m][j], 1);
            rs[m][j] += __shfl_xor(rs[m][j], 2);
            rs[m][j] += __shfl_xor(rs[m][j], 4);
            rs[m][j] += __shfl_xor(rs[m][j], 8);
        }
    __syncthreads();
    float* nrm = (float*)smem;     // [192][2]
    if (lm == 0) {
#pragma unroll
        for (int m = 0; m < 6; ++m) {
            int mh = m / 3, mi = m % 3;
#pragma unroll
            for (int j = 0; j < 4; ++j) {
                int row = wm * 96 + mh * 48 + mi * 16 + lg4 * 4 + j;
                nrm[row * 2 + wn] = rs[m][j];
            }
        }
    }
    __syncthreads();
    if (t < 192) rpnp[(size_t)nt * 36864 + Mb + t] = nrm[t * 2] + nrm[t * 2 + 1];
}

// ---------------- norm: rpn = rsqrt(sum of 6 partials) ----------------
__global__ void pcl_norm(const float* __restrict__ rpnp, float* __restrict__ rpn) {
    int i = blockIdx.x * 256 + threadIdx.x;   // 144 x 256 = 36864
    float s = 0.f;
#pragma unroll
    for (int nt = 0; nt < 6; ++nt) s += rpnp[(size_t)nt * 36864 + i];
    rpn[i] = 1.0f / sqrtf(s);
}

// ================= K2: score GEMM 192x128, 2-phase 1-barrier/K-tile (R10-proven) =====
#define K2_LDS 81920

__global__ __launch_bounds__(256, 2)
void pcl_k2(const unsigned short* __restrict__ pbuf,
            const unsigned short* __restrict__ wsL,
            const float* __restrict__ rpn,
            double* __restrict__ partials) {
    extern __shared__ char smem[];
    const int t = threadIdx.x, w = t >> 6, l = t & 63;
    const int wg = (blockIdx.x & 7) * 384 + (blockIdx.x >> 3);   // bijective XCD remap
    const int mt = wg >> 4, nt = wg & 15;
    const size_t Mb = (size_t)mt * 192;
    const int Nb = nt * 128;
    const int wm = w >> 1, wn = w & 1;
    const int ir = l >> 3, s2 = (l & 7) ^ ir;
    const int lm = l & 15, lg4 = l >> 4;

    char* buf0 = smem;
    char* buf1 = smem + 40960;

    auto stage = [&](int kt, char* buf) {            // A 6 + B 4 chunks per wave
#pragma unroll
        for (int rr = 0; rr < 6; ++rr) {
            int c2 = w * 6 + rr;                     // 0..23
            gl16(pbuf + (Mb + c2 * 8 + ir) * 768 + kt * 64 + s2 * 8, buf + c2 * 1024);
        }
#pragma unroll
        for (int rr = 0; rr < 4; ++rr) {
            int c2 = w * 4 + rr;                     // 0..15
            gl16(wsL + (size_t)(Nb + c2 * 8 + ir) * 768 + kt * 64 + s2 * 8,
                 buf + 24576 + c2 * 1024);
        }
    };

    f32x4 acc[6][4];
#pragma unroll
    for (int m = 0; m < 6; ++m)
#pragma unroll
        for (int nb = 0; nb < 4; ++nb) acc[m][nb] = (f32x4)0.f;

    stage(0, buf0);
    VW0(); BAR();

    bf16x8 areg[3][2], breg[4][2];

#pragma unroll 2
    for (int kt = 0; kt < 12; ++kt) {
        char* cur = (kt & 1) ? buf1 : buf0;
        char* nxt = (kt & 1) ? buf0 : buf1;

        if (kt < 11) stage(kt + 1, nxt);

#pragma unroll
        for (int nb = 0; nb < 4; ++nb)
#pragma unroll
            for (int ks = 0; ks < 2; ++ks) {
                int rb = wn * 64 + nb * 16 + lm, slot = ks * 4 + lg4;
                breg[nb][ks] = *(const bf16x8*)(cur + 24576 + rb * 128 + ((slot ^ (rb & 7)) << 4));
            }
#pragma unroll
        for (int m = 0; m < 3; ++m)
#pragma unroll
            for (int ks = 0; ks < 2; ++ks) {
                int r = wm * 96 + m * 16 + lm, slot = ks * 4 + lg4;
                areg[m][ks] = *(const bf16x8*)(cur + r * 128 + ((slot ^ (r & 7)) << 4));
            }
        __builtin_amdgcn_s_setprio(1);
#pragma unroll
        for (int m = 0; m < 3; ++m)
#pragma unroll
            for (int nb = 0; nb < 4; ++nb)
#pragma unroll
                for (int ks = 0; ks < 2; ++ks)
                    acc[m][nb] = __builtin_amdgcn_mfma_f32_16x16x32_bf16(areg[m][ks], breg[nb][ks], acc[m][nb], 0, 0, 0);
        __builtin_amdgcn_s_setprio(0);

#pragma unroll
        for (int m = 0; m < 3; ++m)
#pragma unroll
            for (int ks = 0; ks < 2; ++ks) {
                int r = wm * 96 + 48 + m * 16 + lm, slot = ks * 4 + lg4;
                areg[m][ks] = *(const bf16x8*)(cur + r * 128 + ((slot ^ (r & 7)) << 4));
            }
        __builtin_amdgcn_s_setprio(1);
#pragma unroll
        for (int m = 0; m < 3; ++m)
#pragma unroll
            for (int nb = 0; nb < 4; ++nb)
#pragma unroll
                for (int ks = 0; ks < 2; ++ks)
                    acc[3 + m][nb] = __builtin_amdgcn_mfma_f32_16x16x32_bf16(areg[m][ks], breg[nb][ks], acc[3 + m][nb], 0, 0, 0);
        __builtin_amdgcn_s_setprio(0);

        VW0();
        BAR();
    }

    // epilogue: exp(2*cos*rpn); whole tile lies in one batch (192 | 576)
    double ssum = 0.0;
#pragma unroll
    for (int m = 0; m < 6; ++m) {
        int mh = m / 3, mi = m % 3;
        int rl = wm * 96 + mh * 48 + mi * 16;
        float rv[4];
#pragma unroll
        for (int j = 0; j < 4; ++j) rv[j] = rpn[Mb + rl + lg4 * 4 + j];
        float es = 0.f;
#pragma unroll
        for (int nb = 0; nb < 4; ++nb)
#pragma unroll
            for (int j = 0; j < 4; ++j)
                es += __expf(2.0f * acc[m][nb][j] * rv[j]);
        ssum += (double)es;
    }
#pragma unroll
    for (int off = 32; off; off >>= 1) ssum += __shfl_down(ssum, off);
    __syncthreads();
    double* red = (double*)smem;
    if (l == 0) red[w] = ssum;
    __syncthreads();
    if (t == 0) {
        double s = 0.0;
#pragma unroll
        for (int i = 0; i < 4; ++i) s += red[i];
        partials[wg] = s;
    }
}

// ---------------- finish: per-batch gather (3 mt x 16 nt), log-ratio, mean --------
__global__ void pcl_finish(const double* __restrict__ partials, float* __restrict__ out) {
    int b = threadIdx.x;   // 64 batches
    double far = 0.0, close = 0.0;
#pragma unroll
    for (int i = 0; i < 3; ++i) {
        int mt = b * 3 + i;
#pragma unroll
        for (int nTile = 0; nTile < 16; ++nTile) {
            double v = partials[mt * 16 + nTile];
            if (nTile < 8) far += v; else close += v;
        }
    }
    double lb = log(far) - log(close);
#pragma unroll
    for (int off = 32; off; off >>= 1) lb += __shfl_down(lb, off);
    if (b == 0) out[0] = (float)(lb * (1.0 / 64.0));
}

extern "C" void kernel_launch(void* const* d_in, const int* in_sizes, int n_in,
                              void* d_out, int out_size, void* d_ws, size_t ws_size,
                              hipStream_t stream) {
    const float* x    = (const float*)d_in[0];
    const float* w    = (const float*)d_in[1];
    const float* bias = (const float*)d_in[2];
    const float* l1   = (const float*)d_in[3];
    const float* l2   = (const float*)d_in[4];
    float* out = (float*)d_out;

    unsigned short* pbuf = (unsigned short*)d_ws;                       // 36864*768 bf16 P
    unsigned short* wsW  = (unsigned short*)((char*)d_ws + 56623104);   // 768*768 bf16
    unsigned short* wsL  = (unsigned short*)((char*)d_ws + 57802752);   // 2048*768 bf16
    float* rpnp          = (float*)((char*)d_ws + 60948480);            // 6*36864 f32
    float* rpn           = (float*)((char*)d_ws + 61833216);            // 36864 f32
    double* partials     = (double*)((char*)d_ws + 61980672);           // 3072 f64

    (void)hipFuncSetAttribute((const void*)pcl_k1,
                              hipFuncAttributeMaxDynamicSharedMemorySize, K1_LDS);
    (void)hipFuncSetAttribute((const void*)pcl_k2,
                              hipFuncAttributeMaxDynamicSharedMemorySize, K2_LDS);

    pcl_prep_wl<<<2816, 64, 0, stream>>>(w, l1, l2, wsW, wsL);
    pcl_k1<<<1152, 256, K1_LDS, stream>>>(x, wsW, bias, pbuf, rpnp);
    pcl_norm<<<144, 256, 0, stream>>>(rpnp, rpn);
    pcl_k2<<<3072, 256, K2_LDS, stream>>>(pbuf, wsL, rpn, partials);
    pcl_finish<<<1, 64, 0, stream>>>(partials, out);
}

// Round 12
// 194.812 us; speedup vs baseline: 1.9693x; 1.0777x over previous
//
#include <hip/hip_runtime.h>
#include <math.h>

using f32x4  = __attribute__((ext_vector_type(4))) float;
using bf16x8 = __attribute__((ext_vector_type(8))) short;

typedef const __attribute__((address_space(1))) void gas_void;
typedef __attribute__((address_space(3))) void las_void;

__device__ __forceinline__ void gl16(const void* g, void* l) {
    __builtin_amdgcn_global_load_lds((gas_void*)g, (las_void*)l, 16, 0, 0);
}

__device__ __forceinline__ unsigned short f2bf(float f) {
    union { float f; unsigned u; } v; v.f = f;
    unsigned r = v.u + 0x7fffu + ((v.u >> 16) & 1u);   // RNE
    return (unsigned short)(r >> 16);
}
__device__ __forceinline__ float bf2f(unsigned short u) {
    return __uint_as_float(((unsigned)u) << 16);
}

#define VW0() asm volatile("s_waitcnt vmcnt(0)")
#define BAR() __builtin_amdgcn_s_barrier()

// ---------------- prep: X (NCHW fp32) -> patch-major bf16 Xp[36864][768] (R9-proven) ----
__global__ void pcl_prep_x(const float* __restrict__ x, unsigned short* __restrict__ xp) {
    int t = threadIdx.x;              // 256
    int wv = t >> 6, l = t & 63;
    int p = blockIdx.x * 4 + wv;      // patch id
    int b = p / 576, n = p % 576;
    int ph = n / 24, pw = n % 24;
    const float* base = x + ((size_t)(b * 3)) * 147456 + (ph * 16) * 384 + pw * 16;
    unsigned* dst = (unsigned*)(xp + (size_t)p * 768);
#pragma unroll
    for (int q = 0; q < 6; ++q) {
        int k = q * 128 + l * 2;
        int c = k >> 8, i = (k >> 4) & 15, j = k & 15;
        const float* s = base + (size_t)c * 147456 + i * 384 + j;
        float2 v = *(const float2*)s;
        unsigned lo = f2bf(v.x), hi = f2bf(v.y);
        dst[q * 64 + l] = lo | (hi << 16);
    }
}

// ---------------- prep: W -> bf16; latents -> row-normalized bf16 ----------------
__global__ void pcl_prep_wl(const float* __restrict__ w,
                            const float* __restrict__ l1, const float* __restrict__ l2,
                            unsigned short* __restrict__ wsW,
                            unsigned short* __restrict__ wsL) {
    int r = blockIdx.x, t = threadIdx.x;   // 2816 x 64
    if (r < 768) {
        const float* src = w + (size_t)r * 768;
        unsigned short* dst = wsW + (size_t)r * 768;
#pragma unroll
        for (int i = 0; i < 12; ++i) dst[t + 64 * i] = f2bf(src[t + 64 * i]);
    } else {
        int lr = r - 768;
        const float* src = (lr < 1024) ? l1 + (size_t)lr * 768 : l2 + (size_t)(lr - 1024) * 768;
        unsigned short* dst = wsL + (size_t)lr * 768;
        float vals[12];
        float s = 0.f;
#pragma unroll
        for (int i = 0; i < 12; ++i) {
            float f = bf2f(f2bf(src[t + 64 * i]));
            vals[i] = f; s += f * f;
        }
#pragma unroll
        for (int off = 32; off; off >>= 1) s += __shfl_xor(s, off, 64);
        float rn = 1.0f / sqrtf(s);
#pragma unroll
        for (int i = 0; i < 12; ++i) dst[t + 64 * i] = f2bf(vals[i] * rn);
    }
}

// ================= K1': conv GEMM 192x96 tiles, k2-clone, 2 blocks/CU ================
// grid 1536 = 192 mt x 8 nt = 3 exact rounds; XCD remap (8 nt of an mt on one XCD);
// 4 waves 2Mx2N, wave tile 96x48. LDS per buf: A 24K | B 12K; stride 40960 -> 80K.
// Per K-tile: 9 gl16/wave (A6+B3), 18 ds_read_b128, 36 MFMA, 1 barrier.
#define K1_LDS 81920

__global__ __launch_bounds__(256, 2)
void pcl_k1(const unsigned short* __restrict__ xp,
            const unsigned short* __restrict__ wsW,
            const float* __restrict__ bias,
            unsigned short* __restrict__ pbuf,
            float* __restrict__ rpnp) {
    extern __shared__ char smem[];
    const int t = threadIdx.x, w = t >> 6, l = t & 63;
    const int wg = (blockIdx.x & 7) * 192 + (blockIdx.x >> 3);   // bijective XCD remap
    const int mt = wg >> 3, nt = wg & 7;
    const size_t Mb = (size_t)mt * 192;
    const int Nb = nt * 96;
    const int wm = w >> 1, wn = w & 1;
    const int ir = l >> 3, s2 = (l & 7) ^ ir;
    const int lm = l & 15, lg4 = l >> 4;

    char* buf0 = smem;
    char* buf1 = smem + 40960;

    auto stage = [&](int kt, char* buf) {            // A 6 + B 3 chunks per wave
#pragma unroll
        for (int rr = 0; rr < 6; ++rr) {
            int c2 = w * 6 + rr;                     // 0..23
            gl16(xp + (Mb + c2 * 8 + ir) * 768 + kt * 64 + s2 * 8, buf + c2 * 1024);
        }
#pragma unroll
        for (int rr = 0; rr < 3; ++rr) {
            int c2 = w * 3 + rr;                     // 0..11
            gl16(wsW + (size_t)(Nb + c2 * 8 + ir) * 768 + kt * 64 + s2 * 8,
                 buf + 24576 + c2 * 1024);
        }
    };

    f32x4 acc[6][3];
#pragma unroll
    for (int m = 0; m < 6; ++m)
#pragma unroll
        for (int nb = 0; nb < 3; ++nb) acc[m][nb] = (f32x4)0.f;

    stage(0, buf0);
    VW0(); BAR();

    bf16x8 areg[3][2], breg[3][2];

#pragma unroll 2
    for (int kt = 0; kt < 12; ++kt) {
        char* cur = (kt & 1) ? buf1 : buf0;
        char* nxt = (kt & 1) ? buf0 : buf1;

        if (kt < 11) stage(kt + 1, nxt);

        // read b (3 n-frags) + a half0; MFMA mh0
#pragma unroll
        for (int nb = 0; nb < 3; ++nb)
#pragma unroll
            for (int ks = 0; ks < 2; ++ks) {
                int rb = wn * 48 + nb * 16 + lm, slot = ks * 4 + lg4;
                breg[nb][ks] = *(const bf16x8*)(cur + 24576 + rb * 128 + ((slot ^ (rb & 7)) << 4));
            }
#pragma unroll
        for (int m = 0; m < 3; ++m)
#pragma unroll
            for (int ks = 0; ks < 2; ++ks) {
                int r = wm * 96 + m * 16 + lm, slot = ks * 4 + lg4;
                areg[m][ks] = *(const bf16x8*)(cur + r * 128 + ((slot ^ (r & 7)) << 4));
            }
        __builtin_amdgcn_s_setprio(1);
#pragma unroll
        for (int m = 0; m < 3; ++m)
#pragma unroll
            for (int nb = 0; nb < 3; ++nb)
#pragma unroll
                for (int ks = 0; ks < 2; ++ks)
                    acc[m][nb] = __builtin_amdgcn_mfma_f32_16x16x32_bf16(areg[m][ks], breg[nb][ks], acc[m][nb], 0, 0, 0);
        __builtin_amdgcn_s_setprio(0);

        // read a half1; MFMA mh1
#pragma unroll
        for (int m = 0; m < 3; ++m)
#pragma unroll
            for (int ks = 0; ks < 2; ++ks) {
                int r = wm * 96 + 48 + m * 16 + lm, slot = ks * 4 + lg4;
                areg[m][ks] = *(const bf16x8*)(cur + r * 128 + ((slot ^ (r & 7)) << 4));
            }
        __builtin_amdgcn_s_setprio(1);
#pragma unroll
        for (int m = 0; m < 3; ++m)
#pragma unroll
            for (int nb = 0; nb < 3; ++nb)
#pragma unroll
                for (int ks = 0; ks < 2; ++ks)
                    acc[3 + m][nb] = __builtin_amdgcn_mfma_f32_16x16x32_bf16(areg[m][ks], breg[nb][ks], acc[3 + m][nb], 0, 0, 0);
        __builtin_amdgcn_s_setprio(0);

        VW0();
        BAR();
    }

    // ---- epilogue: bias, bf16 P store, partial row sumsq over this block's 96 cols ----
    float rs[6][4];
#pragma unroll
    for (int m = 0; m < 6; ++m)
#pragma unroll
        for (int j = 0; j < 4; ++j) rs[m][j] = 0.f;
#pragma unroll
    for (int nb = 0; nb < 3; ++nb) {
        int d = Nb + wn * 48 + nb * 16 + lm;
        float bv = bias[d];
#pragma unroll
        for (int m = 0; m < 6; ++m) {
            int mh = m / 3, mi = m % 3;
#pragma unroll
            for (int j = 0; j < 4; ++j) {
                int row = wm * 96 + mh * 48 + mi * 16 + lg4 * 4 + j;
                unsigned short h = f2bf(acc[m][nb][j] + bv);
                pbuf[(Mb + row) * 768 + d] = h;
                float fv = bf2f(h);
                rs[m][j] += fv * fv;
            }
        }
    }
#pragma unroll
    for (int m = 0; m < 6; ++m)
#pragma unroll
        for (int j = 0; j < 4; ++j) {
            rs[m][j] += __shfl_xor(rs[m][j], 1);
            rs[m][j] += __shfl_xor(rs[m][j], 2);
            rs[m][j] += __shfl_xor(rs[m][j], 4);
            rs[m][j] += __shfl_xor(rs[m][j], 8);
        }
    __syncthreads();
    float* nrm = (float*)smem;     // [192][2]
    if (lm == 0) {
#pragma unroll
        for (int m = 0; m < 6; ++m) {
            int mh = m / 3, mi = m % 3;
#pragma unroll
            for (int j = 0; j < 4; ++j) {
                int row = wm * 96 + mh * 48 + mi * 16 + lg4 * 4 + j;
                nrm[row * 2 + wn] = rs[m][j];
            }
        }
    }
    __syncthreads();
    if (t < 192) rpnp[(size_t)nt * 36864 + Mb + t] = nrm[t * 2] + nrm[t * 2 + 1];
}

// ---------------- norm: rpn = rsqrt(sum of 8 partials) ----------------
__global__ void pcl_norm(const float* __restrict__ rpnp, float* __restrict__ rpn) {
    int i = blockIdx.x * 256 + threadIdx.x;   // 144 x 256 = 36864
    float s = 0.f;
#pragma unroll
    for (int nt = 0; nt < 8; ++nt) s += rpnp[(size_t)nt * 36864 + i];
    rpn[i] = 1.0f / sqrtf(s);
}

// ================= K2: score GEMM 192x128, 2-phase 1-barrier/K-tile (proven) =========
#define K2_LDS 81920

__global__ __launch_bounds__(256, 2)
void pcl_k2(const unsigned short* __restrict__ pbuf,
            const unsigned short* __restrict__ wsL,
            const float* __restrict__ rpn,
            double* __restrict__ partials) {
    extern __shared__ char smem[];
    const int t = threadIdx.x, w = t >> 6, l = t & 63;
    const int wg = (blockIdx.x & 7) * 384 + (blockIdx.x >> 3);   // bijective XCD remap
    const int mt = wg >> 4, nt = wg & 15;
    const size_t Mb = (size_t)mt * 192;
    const int Nb = nt * 128;
    const int wm = w >> 1, wn = w & 1;
    const int ir = l >> 3, s2 = (l & 7) ^ ir;
    const int lm = l & 15, lg4 = l >> 4;

    char* buf0 = smem;
    char* buf1 = smem + 40960;

    auto stage = [&](int kt, char* buf) {            // A 6 + B 4 chunks per wave
#pragma unroll
        for (int rr = 0; rr < 6; ++rr) {
            int c2 = w * 6 + rr;                     // 0..23
            gl16(pbuf + (Mb + c2 * 8 + ir) * 768 + kt * 64 + s2 * 8, buf + c2 * 1024);
        }
#pragma unroll
        for (int rr = 0; rr < 4; ++rr) {
            int c2 = w * 4 + rr;                     // 0..15
            gl16(wsL + (size_t)(Nb + c2 * 8 + ir) * 768 + kt * 64 + s2 * 8,
                 buf + 24576 + c2 * 1024);
        }
    };

    f32x4 acc[6][4];
#pragma unroll
    for (int m = 0; m < 6; ++m)
#pragma unroll
        for (int nb = 0; nb < 4; ++nb) acc[m][nb] = (f32x4)0.f;

    stage(0, buf0);
    VW0(); BAR();

    bf16x8 areg[3][2], breg[4][2];

#pragma unroll 2
    for (int kt = 0; kt < 12; ++kt) {
        char* cur = (kt & 1) ? buf1 : buf0;
        char* nxt = (kt & 1) ? buf0 : buf1;

        if (kt < 11) stage(kt + 1, nxt);

#pragma unroll
        for (int nb = 0; nb < 4; ++nb)
#pragma unroll
            for (int ks = 0; ks < 2; ++ks) {
                int rb = wn * 64 + nb * 16 + lm, slot = ks * 4 + lg4;
                breg[nb][ks] = *(const bf16x8*)(cur + 24576 + rb * 128 + ((slot ^ (rb & 7)) << 4));
            }
#pragma unroll
        for (int m = 0; m < 3; ++m)
#pragma unroll
            for (int ks = 0; ks < 2; ++ks) {
                int r = wm * 96 + m * 16 + lm, slot = ks * 4 + lg4;
                areg[m][ks] = *(const bf16x8*)(cur + r * 128 + ((slot ^ (r & 7)) << 4));
            }
        __builtin_amdgcn_s_setprio(1);
#pragma unroll
        for (int m = 0; m < 3; ++m)
#pragma unroll
            for (int nb = 0; nb < 4; ++nb)
#pragma unroll
                for (int ks = 0; ks < 2; ++ks)
                    acc[m][nb] = __builtin_amdgcn_mfma_f32_16x16x32_bf16(areg[m][ks], breg[nb][ks], acc[m][nb], 0, 0, 0);
        __builtin_amdgcn_s_setprio(0);

#pragma unroll
        for (int m = 0; m < 3; ++m)
#pragma unroll
            for (int ks = 0; ks < 2; ++ks) {
                int r = wm * 96 + 48 + m * 16 + lm, slot = ks * 4 + lg4;
                areg[m][ks] = *(const bf16x8*)(cur + r * 128 + ((slot ^ (r & 7)) << 4));
            }
        __builtin_amdgcn_s_setprio(1);
#pragma unroll
        for (int m = 0; m < 3; ++m)
#pragma unroll
            for (int nb = 0; nb < 4; ++nb)
#pragma unroll
                for (int ks = 0; ks < 2; ++ks)
                    acc[3 + m][nb] = __builtin_amdgcn_mfma_f32_16x16x32_bf16(areg[m][ks], breg[nb][ks], acc[3 + m][nb], 0, 0, 0);
        __builtin_amdgcn_s_setprio(0);

        VW0();
        BAR();
    }

    // epilogue: exp(2*cos*rpn); whole tile lies in one batch (192 | 576)
    double ssum = 0.0;
#pragma unroll
    for (int m = 0; m < 6; ++m) {
        int mh = m / 3, mi = m % 3;
        int rl = wm * 96 + mh * 48 + mi * 16;
        float rv[4];
#pragma unroll
        for (int j = 0; j < 4; ++j) rv[j] = rpn[Mb + rl + lg4 * 4 + j];
        float es = 0.f;
#pragma unroll
        for (int nb = 0; nb < 4; ++nb)
#pragma unroll
            for (int j = 0; j < 4; ++j)
                es += __expf(2.0f * acc[m][nb][j] * rv[j]);
        ssum += (double)es;
    }
#pragma unroll
    for (int off = 32; off; off >>= 1) ssum += __shfl_down(ssum, off);
    __syncthreads();
    double* red = (double*)smem;
    if (l == 0) red[w] = ssum;
    __syncthreads();
    if (t == 0) {
        double s = 0.0;
#pragma unroll
        for (int i = 0; i < 4; ++i) s += red[i];
        partials[wg] = s;
    }
}

// ---------------- finish: per-batch gather (3 mt x 16 nt), log-ratio, mean --------
__global__ void pcl_finish(const double* __restrict__ partials, float* __restrict__ out) {
    int b = threadIdx.x;   // 64 batches
    double far = 0.0, close = 0.0;
#pragma unroll
    for (int i = 0; i < 3; ++i) {
        int mt = b * 3 + i;
#pragma unroll
        for (int nTile = 0; nTile < 16; ++nTile) {
            double v = partials[mt * 16 + nTile];
            if (nTile < 8) far += v; else close += v;
        }
    }
    double lb = log(far) - log(close);
#pragma unroll
    for (int off = 32; off; off >>= 1) lb += __shfl_down(lb, off);
    if (b == 0) out[0] = (float)(lb * (1.0 / 64.0));
}

extern "C" void kernel_launch(void* const* d_in, const int* in_sizes, int n_in,
                              void* d_out, int out_size, void* d_ws, size_t ws_size,
                              hipStream_t stream) {
    const float* x    = (const float*)d_in[0];
    const float* w    = (const float*)d_in[1];
    const float* bias = (const float*)d_in[2];
    const float* l1   = (const float*)d_in[3];
    const float* l2   = (const float*)d_in[4];
    float* out = (float*)d_out;

    unsigned short* xp   = (unsigned short*)d_ws;                        // 36864*768 bf16 X
    unsigned short* pbuf = (unsigned short*)((char*)d_ws + 56623104);    // 36864*768 bf16 P
    unsigned short* wsW  = (unsigned short*)((char*)d_ws + 113246208);   // 768*768 bf16
    unsigned short* wsL  = (unsigned short*)((char*)d_ws + 114425856);   // 2048*768 bf16
    float* rpnp          = (float*)((char*)d_ws + 117571584);            // 8*36864 f32
    float* rpn           = (float*)((char*)d_ws + 118751232);            // 36864 f32
    double* partials     = (double*)((char*)d_ws + 118898688);           // 3072 f64

    (void)hipFuncSetAttribute((const void*)pcl_k1,
                              hipFuncAttributeMaxDynamicSharedMemorySize, K1_LDS);
    (void)hipFuncSetAttribute((const void*)pcl_k2,
                              hipFuncAttributeMaxDynamicSharedMemorySize, K2_LDS);

    pcl_prep_x<<<9216, 256, 0, stream>>>(x, xp);
    pcl_prep_wl<<<2816, 64, 0, stream>>>(w, l1, l2, wsW, wsL);
    pcl_k1<<<1536, 256, K1_LDS, stream>>>(xp, wsW, bias, pbuf, rpnp);
    pcl_norm<<<144, 256, 0, stream>>>(rpnp, rpn);
    pcl_k2<<<3072, 256, K2_LDS, stream>>>(pbuf, wsL, rpn, partials);
    pcl_finish<<<1, 64, 0, stream>>>(partials, out);
}